// Round 6
// baseline (1689.866 us; speedup 1.0000x reference)
//
#include <hip/hip_runtime.h>
#include <hip/hip_bf16.h>
#include <math.h>

#define NN 50000
#define EDGES 1600000
#define ETOT (EDGES + NN)
#define FINDIM 39

// ---------------- edge_index dtype sniffer (int64 safety net) ----------------
__global__ void detect_kernel(const int* __restrict__ ei, int* __restrict__ flag) {
    int t = blockIdx.x * blockDim.x + threadIdx.x;   // 4096 threads
    if (ei[2 * t + 1] != 0) atomicOr(flag, 1);       // flag=1 -> int32
}

__device__ __forceinline__ int src_at(const int* ei, int i, bool i32) {
    return i32 ? ei[i] : ei[2 * i];
}
__device__ __forceinline__ int dst_at(const int* ei, int i, bool i32) {
    return i32 ? ei[EDGES + i] : ei[2 * (EDGES + i)];
}

// ---------------- CSR build ----------------
__global__ void hist_kernel(const int* __restrict__ ei, const int* __restrict__ flag,
                            int* __restrict__ cnt) {
    int idx = blockIdx.x * blockDim.x + threadIdx.x;
    if (idx >= ETOT) return;
    bool i32 = (*flag != 0);
    int d = (idx < EDGES) ? dst_at(ei, idx, i32) : (idx - EDGES);
    atomicAdd(&cnt[d], 1);
}

__global__ __launch_bounds__(256) void scan_kernel(const int* __restrict__ cnt,
                                                   int* __restrict__ rowptr,
                                                   int* __restrict__ cursor) {
    __shared__ int psum[256];
    const int CH = (NN + 255) / 256;
    int t = threadIdx.x;
    int lo = t * CH, hi = lo + CH; if (hi > NN) hi = NN;
    int s = 0;
    for (int i = lo; i < hi; ++i) s += cnt[i];
    psum[t] = s;
    __syncthreads();
    if (t == 0) {
        int run = 0;
        for (int i = 0; i < 256; ++i) { int v = psum[i]; psum[i] = run; run += v; }
        rowptr[NN] = run;
    }
    __syncthreads();
    int run = psum[t];
    for (int i = lo; i < hi; ++i) {
        rowptr[i] = run; cursor[i] = run; run += cnt[i];
    }
}

__global__ void scatter_kernel(const int* __restrict__ ei, const int* __restrict__ flag,
                               int* __restrict__ cursor, int* __restrict__ colidx) {
    int idx = blockIdx.x * blockDim.x + threadIdx.x;
    if (idx >= ETOT) return;
    bool i32 = (*flag != 0);
    int s, d;
    if (idx < EDGES) { s = src_at(ei, idx, i32); d = dst_at(ei, idx, i32); }
    else { s = d = idx - EDGES; }
    int pos = atomicAdd(&cursor[d], 1);
    colidx[pos] = s;
}

// ---------------- GEMM: C[M,NC] = act(A[M,K] @ B[K,NC] + bias), all fp32 ----------------
template <int NC, bool RELU>
__global__ __launch_bounds__(256) void gemm_kernel(const float* __restrict__ A,
                                                   const float* __restrict__ B,
                                                   const float* __restrict__ bias,
                                                   float* __restrict__ C, int M, int K) {
    constexpr int TM = 32;
    constexpr int GROUPS = 256 / NC;     // 2 for NC=128, 4 for NC=64
    constexpr int RPG = TM / GROUPS;     // 16 / 8
    constexpr int KC = 64;               // K-chunk for B staging
    __shared__ float As[TM * 128];       // 16 KB (full K <= 128)
    __shared__ float Bs[KC * NC];        // 32 KB (NC=128) / 16 KB (NC=64)
    int t = threadIdx.x;
    int i0 = blockIdx.x * TM;

    int rows = M - i0; if (rows > TM) rows = TM;
    for (int idx = t; idx < rows * K; idx += 256) {
        int r = idx / K, k = idx - r * K;
        As[r * K + k] = A[(size_t)(i0 + r) * K + k];
    }

    int col = t % NC, grp = t / NC;
    int rg0 = grp * RPG;
    float acc[RPG];
#pragma unroll
    for (int r = 0; r < RPG; ++r) acc[r] = 0.f;

    for (int k0 = 0; k0 < K; k0 += KC) {
        int kc = K - k0; if (kc > KC) kc = KC;
        __syncthreads();                 // As ready (iter 0) / Bs consumed (iter >0)
        for (int idx = t; idx < kc * NC; idx += 256) Bs[idx] = B[(size_t)k0 * NC + idx];
        __syncthreads();
        for (int k = 0; k < kc; ++k) {
            float bv = Bs[k * NC + col];
#pragma unroll
            for (int r = 0; r < RPG; ++r) acc[r] += As[(rg0 + r) * K + k0 + k] * bv;
        }
    }

    float bb = bias ? bias[col] : 0.f;
#pragma unroll
    for (int r = 0; r < RPG; ++r) {
        int i = i0 + rg0 + r;
        if (i < M) {
            float v = acc[r] + bb;
            if (RELU) v = v > 0.f ? v : 0.f;
            C[(size_t)i * NC + col] = v;
        }
    }
}

// ---------------- es/ed: one thread per (node, head) ----------------
__global__ void attn_prep_kernel(const float* __restrict__ xp,
                                 const float* __restrict__ a_s,
                                 const float* __restrict__ a_d,
                                 float* __restrict__ es, float* __restrict__ ed) {
    int idx = blockIdx.x * blockDim.x + threadIdx.x;   // i*4 + h
    if (idx >= NN * 4) return;
    int i = idx >> 2, h = idx & 3;
    const float* xr = xp + (size_t)i * 128 + h * 32;
    float ss = 0.f, sd = 0.f;
    for (int c = 0; c < 32; ++c) {
        float v = xr[c];
        ss += v * a_s[h * 32 + c];
        sd += v * a_d[h * 32 + c];
    }
    es[idx] = ss;
    ed[idx] = sd;
}

// ---------------- per-node block: softmax-agg + bias + residual + LN + relu ----------------
__global__ __launch_bounds__(128) void gat_agg_ln_kernel(
    const float* __restrict__ xp, const float* __restrict__ es, const float* __restrict__ ed,
    const int* __restrict__ rowptr, const int* __restrict__ colidx,
    const float* __restrict__ h_in,
    const float* __restrict__ bc, const float* __restrict__ g, const float* __restrict__ be,
    float* __restrict__ h_out) {
    int v = blockIdx.x;
    int c = threadIdx.x;          // channel 0..127
    int h = c >> 5;               // head
    int s0 = rowptr[v], s1 = rowptr[v + 1];
    float edv = ed[v * 4 + h];

    float m = -1e30f;
    for (int p = s0; p < s1; ++p) {
        int u = colidx[p];
        float e = es[u * 4 + h] + edv;
        e = e > 0.f ? e : 0.2f * e;
        m = fmaxf(m, e);
    }
    float acc = 0.f, den = 0.f;
    for (int p = s0; p < s1; ++p) {
        int u = colidx[p];
        float e = es[u * 4 + h] + edv;
        e = e > 0.f ? e : 0.2f * e;
        float w = __expf(e - m);
        den += w;
        acc += w * xp[(size_t)u * 128 + c];
    }

    float y = acc / den + bc[c] + h_in[(size_t)v * 128 + c];

    __shared__ float red[128];
    red[c] = y;
    __syncthreads();
    for (int s = 64; s > 0; s >>= 1) {
        if (c < s) red[c] += red[c + s];
        __syncthreads();
    }
    float mean = red[0] * (1.f / 128.f);
    __syncthreads();
    float d = y - mean;
    red[c] = d * d;
    __syncthreads();
    for (int s = 64; s > 0; s >>= 1) {
        if (c < s) red[c] += red[c + s];
        __syncthreads();
    }
    float rstd = rsqrtf(red[0] * (1.f / 128.f) + 1e-5f);
    float z = d * rstd * g[c] + be[c];
    h_out[(size_t)v * 128 + c] = z > 0.f ? z : 0.f;
}

// ---------------- output heads: fp32 out (impact [N,3] then timing [N,2]) ----------------
__global__ void heads_kernel(const float* __restrict__ imp1, const float* __restrict__ tim1,
                             const float* __restrict__ iw2, const float* __restrict__ ib2,
                             const float* __restrict__ tw2, const float* __restrict__ tb2,
                             float* __restrict__ out) {
    int idx = blockIdx.x * blockDim.x + threadIdx.x;
    if (idx >= NN * 5) return;
    int i = idx / 5, j = idx - i * 5;
    if (j < 3) {
        float acc = ib2[j];
        const float* r = imp1 + (size_t)i * 64;
        for (int k = 0; k < 64; ++k) acc += r[k] * iw2[k * 3 + j];
        out[(size_t)i * 3 + j] = acc;
    } else {
        int jj = j - 3;
        float acc = tb2[jj];
        const float* r = tim1 + (size_t)i * 64;
        for (int k = 0; k < 64; ++k) acc += r[k] * tw2[k * 2 + jj];
        float sp = acc > 20.f ? acc : log1pf(__expf(acc));
        out[(size_t)(NN * 3) + (size_t)i * 2 + jj] = sp;
    }
}

extern "C" void kernel_launch(void* const* d_in, const int* in_sizes, int n_in,
                              void* d_out, int out_size, void* d_ws, size_t ws_size,
                              hipStream_t stream) {
    const float* x      = (const float*)d_in[0];
    const int*   ei     = (const int*)d_in[1];
    const float* enc_w1 = (const float*)d_in[2];
    const float* enc_b1 = (const float*)d_in[3];
    const float* enc_w2 = (const float*)d_in[4];
    const float* enc_b2 = (const float*)d_in[5];
    const float *W[3], *as_[3], *ad_[3], *bc[3], *g[3], *be[3];
    for (int l = 0; l < 3; ++l) {
        W[l]   = (const float*)d_in[6 + l * 6 + 0];
        as_[l] = (const float*)d_in[6 + l * 6 + 1];
        ad_[l] = (const float*)d_in[6 + l * 6 + 2];
        bc[l]  = (const float*)d_in[6 + l * 6 + 3];
        g[l]   = (const float*)d_in[6 + l * 6 + 4];
        be[l]  = (const float*)d_in[6 + l * 6 + 5];
    }
    const float* imp_w1 = (const float*)d_in[24];
    const float* imp_b1 = (const float*)d_in[25];
    const float* imp_w2 = (const float*)d_in[26];
    const float* imp_b2 = (const float*)d_in[27];
    const float* tim_w1 = (const float*)d_in[28];
    const float* tim_b1 = (const float*)d_in[29];
    const float* tim_w2 = (const float*)d_in[30];
    const float* tim_b2 = (const float*)d_in[31];

    int* flag   = (int*)d_ws;
    int* cnt    = flag + 64;
    int* cursor = cnt + NN;
    int* rowptr = cursor + NN;
    int* colidx = rowptr + (NN + 1);
    uintptr_t fb = (uintptr_t)(colidx + ETOT);
    fb = (fb + 255) & ~(uintptr_t)255;
    float* es = (float*)fb;
    float* ed = es + (size_t)NN * 4;
    float* hA = ed + (size_t)NN * 4;
    float* hB = hA + (size_t)NN * 128;
    float* xp = hB + (size_t)NN * 128;
    float* tmp = xp;   // aliased: tmp dead before xp lives, and vice versa

    hipMemsetAsync(flag, 0, sizeof(int), stream);
    hipMemsetAsync(cnt, 0, NN * sizeof(int), stream);
    detect_kernel<<<16, 256, 0, stream>>>(ei, flag);
    hist_kernel<<<(ETOT + 255) / 256, 256, 0, stream>>>(ei, flag, cnt);
    scan_kernel<<<1, 256, 0, stream>>>(cnt, rowptr, cursor);
    scatter_kernel<<<(ETOT + 255) / 256, 256, 0, stream>>>(ei, flag, cursor, colidx);

    const int GB = (NN + 31) / 32;
    gemm_kernel<128, true><<<GB, 256, 0, stream>>>(x, enc_w1, enc_b1, tmp, NN, FINDIM);
    gemm_kernel<128, false><<<GB, 256, 0, stream>>>(tmp, enc_w2, enc_b2, hA, NN, 128);

    float* hcur = hA;
    float* hnext = hB;
    for (int l = 0; l < 3; ++l) {
        gemm_kernel<128, false><<<GB, 256, 0, stream>>>(hcur, W[l], nullptr, xp, NN, 128);
        attn_prep_kernel<<<(NN * 4 + 255) / 256, 256, 0, stream>>>(xp, as_[l], ad_[l], es, ed);
        gat_agg_ln_kernel<<<NN, 128, 0, stream>>>(xp, es, ed, rowptr, colidx, hcur,
                                                  bc[l], g[l], be[l], hnext);
        float* t2 = hcur; hcur = hnext; hnext = t2;
    }

    float* imp1 = tmp;
    float* tim1 = tmp + (size_t)NN * 64;
    gemm_kernel<64, true><<<GB, 256, 0, stream>>>(hcur, imp_w1, imp_b1, imp1, NN, 128);
    gemm_kernel<64, true><<<GB, 256, 0, stream>>>(hcur, tim_w1, tim_b1, tim1, NN, 128);
    heads_kernel<<<(NN * 5 + 255) / 256, 256, 0, stream>>>(imp1, tim1, imp_w2, imp_b2,
                                                           tim_w2, tim_b2, (float*)d_out);
}

// Round 7
// 1136.477 us; speedup vs baseline: 1.4869x; 1.4869x over previous
//
#include <hip/hip_runtime.h>
#include <hip/hip_bf16.h>
#include <math.h>

#define NN 50000
#define EDGES 1600000
#define ETOT (EDGES + NN)
#define FINDIM 39

// ---------------- edge_index dtype sniffer (int64 safety net) ----------------
__global__ void detect_kernel(const int* __restrict__ ei, int* __restrict__ flag) {
    int t = blockIdx.x * blockDim.x + threadIdx.x;   // 4096 threads
    if (ei[2 * t + 1] != 0) atomicOr(flag, 1);       // flag=1 -> int32
}

__device__ __forceinline__ int src_at(const int* ei, int i, bool i32) {
    return i32 ? ei[i] : ei[2 * i];
}
__device__ __forceinline__ int dst_at(const int* ei, int i, bool i32) {
    return i32 ? ei[EDGES + i] : ei[2 * (EDGES + i)];
}

// ---------------- CSR build ----------------
__global__ void hist_kernel(const int* __restrict__ ei, const int* __restrict__ flag,
                            int* __restrict__ cnt) {
    int idx = blockIdx.x * blockDim.x + threadIdx.x;
    if (idx >= ETOT) return;
    bool i32 = (*flag != 0);
    int d = (idx < EDGES) ? dst_at(ei, idx, i32) : (idx - EDGES);
    atomicAdd(&cnt[d], 1);
}

__global__ __launch_bounds__(256) void scan_kernel(const int* __restrict__ cnt,
                                                   int* __restrict__ rowptr,
                                                   int* __restrict__ cursor) {
    __shared__ int psum[256];
    const int CH = (NN + 255) / 256;
    int t = threadIdx.x;
    int lo = t * CH, hi = lo + CH; if (hi > NN) hi = NN;
    int s = 0;
    for (int i = lo; i < hi; ++i) s += cnt[i];
    psum[t] = s;
    __syncthreads();
    if (t == 0) {
        int run = 0;
        for (int i = 0; i < 256; ++i) { int v = psum[i]; psum[i] = run; run += v; }
        rowptr[NN] = run;
    }
    __syncthreads();
    int run = psum[t];
    for (int i = lo; i < hi; ++i) {
        rowptr[i] = run; cursor[i] = run; run += cnt[i];
    }
}

__global__ void scatter_kernel(const int* __restrict__ ei, const int* __restrict__ flag,
                               int* __restrict__ cursor, int* __restrict__ colidx) {
    int idx = blockIdx.x * blockDim.x + threadIdx.x;
    if (idx >= ETOT) return;
    bool i32 = (*flag != 0);
    int s, d;
    if (idx < EDGES) { s = src_at(ei, idx, i32); d = dst_at(ei, idx, i32); }
    else { s = d = idx - EDGES; }
    int pos = atomicAdd(&cursor[d], 1);
    colidx[pos] = s;
}

// ---------------- generic GEMM (only for K=39 encoder-1) ----------------
template <int NC, bool RELU>
__global__ __launch_bounds__(256) void gemm_small_kernel(const float* __restrict__ A,
                                                         const float* __restrict__ B,
                                                         const float* __restrict__ bias,
                                                         float* __restrict__ C, int M, int K) {
    constexpr int TM = 32;
    constexpr int GROUPS = 256 / NC;
    constexpr int RPG = TM / GROUPS;
    constexpr int KC = 64;
    __shared__ float As[TM * 128];
    __shared__ float Bs[KC * NC];
    int t = threadIdx.x;
    int i0 = blockIdx.x * TM;

    int rows = M - i0; if (rows > TM) rows = TM;
    for (int idx = t; idx < rows * K; idx += 256) {
        int r = idx / K, k = idx - r * K;
        As[r * K + k] = A[(size_t)(i0 + r) * K + k];
    }

    int col = t % NC, grp = t / NC;
    int rg0 = grp * RPG;
    float acc[RPG];
#pragma unroll
    for (int r = 0; r < RPG; ++r) acc[r] = 0.f;

    for (int k0 = 0; k0 < K; k0 += KC) {
        int kc = K - k0; if (kc > KC) kc = KC;
        __syncthreads();
        for (int idx = t; idx < kc * NC; idx += 256) Bs[idx] = B[(size_t)k0 * NC + idx];
        __syncthreads();
        for (int k = 0; k < kc; ++k) {
            float bv = Bs[k * NC + col];
#pragma unroll
            for (int r = 0; r < RPG; ++r) acc[r] += As[(rg0 + r) * K + k0 + k] * bv;
        }
    }

    float bb = bias ? bias[col] : 0.f;
#pragma unroll
    for (int r = 0; r < RPG; ++r) {
        int i = i0 + rg0 + r;
        if (i < M) {
            float v = acc[r] + bb;
            if (RELU) v = v > 0.f ? v : 0.f;
            C[(size_t)i * NC + col] = v;
        }
    }
}

// ---------------- fast GEMM: C[M,128] = act(A[M,128] @ B[128,128] + bias) ----------------
template <bool RELU>
__global__ __launch_bounds__(256) void gemm128_kernel(const float* __restrict__ A,
                                                      const float* __restrict__ B,
                                                      const float* __restrict__ bias,
                                                      float* __restrict__ C, int M) {
    __shared__ float As[64 * 128];   // 32 KB, full K
    __shared__ float Bs[64 * 128];   // 32 KB, K-chunk
    int t = threadIdx.x;
    int i0 = blockIdx.x * 64;
    int tc = t & 31;                 // cols: tc + 32j, j=0..3
    int tr = t >> 5;                 // rows: tr*8 .. tr*8+7
    int r0 = tr * 8;

    // stage As (full 64 rows x 128 k), guarded
    for (int idx = t * 4; idx < 64 * 128; idx += 1024) {
        int r = idx >> 7, k = idx & 127;
        float4 v4 = make_float4(0.f, 0.f, 0.f, 0.f);
        if (i0 + r < M) v4 = *(const float4*)&A[(size_t)(i0 + r) * 128 + k];
        *(float4*)&As[idx] = v4;
    }

    float acc[8][4];
#pragma unroll
    for (int i = 0; i < 8; ++i)
#pragma unroll
        for (int j = 0; j < 4; ++j) acc[i][j] = 0.f;

    for (int k0 = 0; k0 < 128; k0 += 64) {
        __syncthreads();             // As ready / prev Bs consumed
        for (int idx = t * 4; idx < 64 * 128; idx += 1024)
            *(float4*)&Bs[idx] = *(const float4*)&B[(size_t)k0 * 128 + idx];
        __syncthreads();
#pragma unroll 4
        for (int k = 0; k < 64; k += 4) {
            float4 a4[8];
#pragma unroll
            for (int i = 0; i < 8; ++i)
                a4[i] = *(const float4*)&As[(r0 + i) * 128 + k0 + k];
            float bb[4][4];
#pragma unroll
            for (int kk = 0; kk < 4; ++kk)
#pragma unroll
                for (int j = 0; j < 4; ++j)
                    bb[kk][j] = Bs[(k + kk) * 128 + tc + 32 * j];
#pragma unroll
            for (int i = 0; i < 8; ++i) {
                const float* av = (const float*)&a4[i];
#pragma unroll
                for (int kk = 0; kk < 4; ++kk)
#pragma unroll
                    for (int j = 0; j < 4; ++j)
                        acc[i][j] += av[kk] * bb[kk][j];
            }
        }
    }

#pragma unroll
    for (int i = 0; i < 8; ++i) {
        int row = i0 + r0 + i;
        if (row < M) {
#pragma unroll
            for (int j = 0; j < 4; ++j) {
                int col = tc + 32 * j;
                float v = acc[i][j] + (bias ? bias[col] : 0.f);
                if (RELU) v = v > 0.f ? v : 0.f;
                C[(size_t)row * 128 + col] = v;
            }
        }
    }
}

// ---------------- merged head GEMMs: [imp1|tim1] = relu(A @ [iw1|tw1] + [ib1|tb1]) ----------------
__global__ __launch_bounds__(256) void gemm_heads_kernel(const float* __restrict__ A,
                                                         const float* __restrict__ iw1,
                                                         const float* __restrict__ ib1,
                                                         const float* __restrict__ tw1,
                                                         const float* __restrict__ tb1,
                                                         float* __restrict__ imp1,
                                                         float* __restrict__ tim1, int M) {
    __shared__ float As[64 * 128];
    __shared__ float Bs[64 * 128];
    int t = threadIdx.x;
    int i0 = blockIdx.x * 64;
    int tc = t & 31;
    int tr = t >> 5;
    int r0 = tr * 8;

    for (int idx = t * 4; idx < 64 * 128; idx += 1024) {
        int r = idx >> 7, k = idx & 127;
        float4 v4 = make_float4(0.f, 0.f, 0.f, 0.f);
        if (i0 + r < M) v4 = *(const float4*)&A[(size_t)(i0 + r) * 128 + k];
        *(float4*)&As[idx] = v4;
    }

    float acc[8][4];
#pragma unroll
    for (int i = 0; i < 8; ++i)
#pragma unroll
        for (int j = 0; j < 4; ++j) acc[i][j] = 0.f;

    for (int k0 = 0; k0 < 128; k0 += 64) {
        __syncthreads();
        for (int idx = t * 4; idx < 64 * 128; idx += 1024) {
            int k = idx >> 7, cl = idx & 127;   // virtual col 0..127
            float4 v4 = (cl < 64)
                ? *(const float4*)&iw1[(size_t)(k0 + k) * 64 + cl]
                : *(const float4*)&tw1[(size_t)(k0 + k) * 64 + (cl - 64)];
            *(float4*)&Bs[idx] = v4;
        }
        __syncthreads();
#pragma unroll 4
        for (int k = 0; k < 64; k += 4) {
            float4 a4[8];
#pragma unroll
            for (int i = 0; i < 8; ++i)
                a4[i] = *(const float4*)&As[(r0 + i) * 128 + k0 + k];
            float bb[4][4];
#pragma unroll
            for (int kk = 0; kk < 4; ++kk)
#pragma unroll
                for (int j = 0; j < 4; ++j)
                    bb[kk][j] = Bs[(k + kk) * 128 + tc + 32 * j];
#pragma unroll
            for (int i = 0; i < 8; ++i) {
                const float* av = (const float*)&a4[i];
#pragma unroll
                for (int kk = 0; kk < 4; ++kk)
#pragma unroll
                    for (int j = 0; j < 4; ++j)
                        acc[i][j] += av[kk] * bb[kk][j];
            }
        }
    }

#pragma unroll
    for (int i = 0; i < 8; ++i) {
        int row = i0 + r0 + i;
        if (row < M) {
#pragma unroll
            for (int j = 0; j < 4; ++j) {
                int col = tc + 32 * j;
                float b = (col < 64) ? ib1[col] : tb1[col - 64];
                float v = acc[i][j] + b;
                v = v > 0.f ? v : 0.f;
                if (col < 64) imp1[(size_t)row * 64 + col] = v;
                else          tim1[(size_t)row * 64 + (col - 64)] = v;
            }
        }
    }
}

// ---------------- es/ed: coalesced, block = 2 nodes, 32-lane shuffle reduce ----------------
__global__ __launch_bounds__(256) void attn_prep_kernel(const float* __restrict__ xp,
                                                        const float* __restrict__ a_s,
                                                        const float* __restrict__ a_d,
                                                        float* __restrict__ es,
                                                        float* __restrict__ ed) {
    int t = threadIdx.x;
    int i = blockIdx.x * 2 + (t >> 7);
    int c = t & 127;
    float v = xp[(size_t)i * 128 + c];
    float ps = v * a_s[c];
    float pd = v * a_d[c];
#pragma unroll
    for (int off = 16; off >= 1; off >>= 1) {
        ps += __shfl_xor(ps, off);
        pd += __shfl_xor(pd, off);
    }
    if ((c & 31) == 0) {
        es[i * 4 + (c >> 5)] = ps;
        ed[i * 4 + (c >> 5)] = pd;
    }
}

// ---------------- gat: single-pass (no max; |e| small), LDS-staged weights ----------------
#define GTILE 128
__global__ __launch_bounds__(128) void gat_agg_ln_kernel(
    const float* __restrict__ xp, const float* __restrict__ es, const float* __restrict__ ed,
    const int* __restrict__ rowptr, const int* __restrict__ colidx,
    const float* __restrict__ h_in,
    const float* __restrict__ bc, const float* __restrict__ g, const float* __restrict__ be,
    float* __restrict__ h_out) {
    __shared__ int   uu[GTILE];
    __shared__ float ww[GTILE * 4];
    __shared__ float eds[4];
    __shared__ float red[128];
    int v = blockIdx.x;
    int c = threadIdx.x;          // channel 0..127
    int h = c >> 5;               // head
    int s0 = rowptr[v], s1 = rowptr[v + 1];
    if (c < 4) eds[c] = ed[v * 4 + c];

    float acc = 0.f, den = 0.f;
    for (int p0 = s0; p0 < s1; p0 += GTILE) {
        int n = s1 - p0; if (n > GTILE) n = GTILE;
        __syncthreads();          // eds ready (1st iter) / LDS consumed (later)
        for (int idx = c; idx < n * 4; idx += 128) {
            int p = idx >> 2, hh = idx & 3;
            int u = colidx[p0 + p];
            if (hh == 0) uu[p] = u;
            float e = es[u * 4 + hh] + eds[hh];
            e = e > 0.f ? e : 0.2f * e;
            ww[idx] = __expf(e);  // exp(e - m) / sum == exp(e) / sum ; |e| small
        }
        __syncthreads();
#pragma unroll 2
        for (int p = 0; p < n; ++p) {
            int u = uu[p];
            float w = ww[p * 4 + h];
            den += w;
            acc += w * xp[(unsigned)(u * 128 + c)];
        }
    }

    float y = acc / den + bc[c] + h_in[(size_t)v * 128 + c];

    red[c] = y;
    __syncthreads();
    for (int s = 64; s > 0; s >>= 1) {
        if (c < s) red[c] += red[c + s];
        __syncthreads();
    }
    float mean = red[0] * (1.f / 128.f);
    __syncthreads();
    float d = y - mean;
    red[c] = d * d;
    __syncthreads();
    for (int s = 64; s > 0; s >>= 1) {
        if (c < s) red[c] += red[c + s];
        __syncthreads();
    }
    float rstd = rsqrtf(red[0] * (1.f / 128.f) + 1e-5f);
    float z = d * rstd * g[c] + be[c];
    h_out[(size_t)v * 128 + c] = z > 0.f ? z : 0.f;
}

// ---------------- output heads: fp32 out (impact [N,3] then timing [N,2]) ----------------
__global__ void heads_kernel(const float* __restrict__ imp1, const float* __restrict__ tim1,
                             const float* __restrict__ iw2, const float* __restrict__ ib2,
                             const float* __restrict__ tw2, const float* __restrict__ tb2,
                             float* __restrict__ out) {
    int idx = blockIdx.x * blockDim.x + threadIdx.x;
    if (idx >= NN * 5) return;
    int i = idx / 5, j = idx - i * 5;
    if (j < 3) {
        float acc = ib2[j];
        const float* r = imp1 + (size_t)i * 64;
        for (int k = 0; k < 64; ++k) acc += r[k] * iw2[k * 3 + j];
        out[(size_t)i * 3 + j] = acc;
    } else {
        int jj = j - 3;
        float acc = tb2[jj];
        const float* r = tim1 + (size_t)i * 64;
        for (int k = 0; k < 64; ++k) acc += r[k] * tw2[k * 2 + jj];
        float sp = acc > 20.f ? acc : log1pf(__expf(acc));
        out[(size_t)(NN * 3) + (size_t)i * 2 + jj] = sp;
    }
}

extern "C" void kernel_launch(void* const* d_in, const int* in_sizes, int n_in,
                              void* d_out, int out_size, void* d_ws, size_t ws_size,
                              hipStream_t stream) {
    const float* x      = (const float*)d_in[0];
    const int*   ei     = (const int*)d_in[1];
    const float* enc_w1 = (const float*)d_in[2];
    const float* enc_b1 = (const float*)d_in[3];
    const float* enc_w2 = (const float*)d_in[4];
    const float* enc_b2 = (const float*)d_in[5];
    const float *W[3], *as_[3], *ad_[3], *bc[3], *g[3], *be[3];
    for (int l = 0; l < 3; ++l) {
        W[l]   = (const float*)d_in[6 + l * 6 + 0];
        as_[l] = (const float*)d_in[6 + l * 6 + 1];
        ad_[l] = (const float*)d_in[6 + l * 6 + 2];
        bc[l]  = (const float*)d_in[6 + l * 6 + 3];
        g[l]   = (const float*)d_in[6 + l * 6 + 4];
        be[l]  = (const float*)d_in[6 + l * 6 + 5];
    }
    const float* imp_w1 = (const float*)d_in[24];
    const float* imp_b1 = (const float*)d_in[25];
    const float* imp_w2 = (const float*)d_in[26];
    const float* imp_b2 = (const float*)d_in[27];
    const float* tim_w1 = (const float*)d_in[28];
    const float* tim_b1 = (const float*)d_in[29];
    const float* tim_w2 = (const float*)d_in[30];
    const float* tim_b2 = (const float*)d_in[31];

    int* flag   = (int*)d_ws;
    int* cnt    = flag + 64;
    int* cursor = cnt + NN;
    int* rowptr = cursor + NN;
    int* colidx = rowptr + (NN + 1);
    uintptr_t fb = (uintptr_t)(colidx + ETOT);
    fb = (fb + 255) & ~(uintptr_t)255;
    float* es = (float*)fb;
    float* ed = es + (size_t)NN * 4;
    float* hA = ed + (size_t)NN * 4;
    float* hB = hA + (size_t)NN * 128;
    float* xp = hB + (size_t)NN * 128;
    float* tmp = xp;   // aliased: tmp dead before xp lives, and vice versa

    hipMemsetAsync(flag, 0, sizeof(int), stream);
    hipMemsetAsync(cnt, 0, NN * sizeof(int), stream);
    detect_kernel<<<16, 256, 0, stream>>>(ei, flag);
    hist_kernel<<<(ETOT + 255) / 256, 256, 0, stream>>>(ei, flag, cnt);
    scan_kernel<<<1, 256, 0, stream>>>(cnt, rowptr, cursor);
    scatter_kernel<<<(ETOT + 255) / 256, 256, 0, stream>>>(ei, flag, cursor, colidx);

    const int GB64 = (NN + 63) / 64;
    gemm_small_kernel<128, true><<<(NN + 31) / 32, 256, 0, stream>>>(x, enc_w1, enc_b1, tmp, NN, FINDIM);
    gemm128_kernel<false><<<GB64, 256, 0, stream>>>(tmp, enc_w2, enc_b2, hA, NN);

    float* hcur = hA;
    float* hnext = hB;
    for (int l = 0; l < 3; ++l) {
        gemm128_kernel<false><<<GB64, 256, 0, stream>>>(hcur, W[l], nullptr, xp, NN);
        attn_prep_kernel<<<NN / 2, 256, 0, stream>>>(xp, as_[l], ad_[l], es, ed);
        gat_agg_ln_kernel<<<NN, 128, 0, stream>>>(xp, es, ed, rowptr, colidx, hcur,
                                                  bc[l], g[l], be[l], hnext);
        float* t2 = hcur; hcur = hnext; hnext = t2;
    }

    float* imp1 = tmp;
    float* tim1 = tmp + (size_t)NN * 64;
    gemm_heads_kernel<<<GB64, 256, 0, stream>>>(hcur, imp_w1, imp_b1, tim_w1, tim_b1,
                                                imp1, tim1, NN);
    heads_kernel<<<(NN * 5 + 255) / 256, 256, 0, stream>>>(imp1, tim1, imp_w2, imp_b2,
                                                           tim_w2, tim_b2, (float*)d_out);
}

// Round 8
// 1002.566 us; speedup vs baseline: 1.6855x; 1.1336x over previous
//
#include <hip/hip_runtime.h>
#include <hip/hip_bf16.h>
#include <math.h>

#define NN 50000
#define EDGES 1600000
#define ETOT (EDGES + NN)
#define FINDIM 39
#define SCAN_B 196   // ceil(50000/256)

// ---------------- edge_index dtype sniffer (int64 safety net) ----------------
__global__ void detect_kernel(const int* __restrict__ ei, int* __restrict__ flag) {
    int t = blockIdx.x * blockDim.x + threadIdx.x;   // 4096 threads
    if (ei[2 * t + 1] != 0) atomicOr(flag, 1);       // flag=1 -> int32
}

__device__ __forceinline__ int src_at(const int* ei, int i, bool i32) {
    return i32 ? ei[i] : ei[2 * i];
}
__device__ __forceinline__ int dst_at(const int* ei, int i, bool i32) {
    return i32 ? ei[EDGES + i] : ei[2 * (EDGES + i)];
}

// ---------------- CSR build ----------------
__global__ void hist_kernel(const int* __restrict__ ei, const int* __restrict__ flag,
                            int* __restrict__ cnt) {
    int idx = blockIdx.x * blockDim.x + threadIdx.x;
    if (idx >= ETOT) return;
    bool i32 = (*flag != 0);
    int d = (idx < EDGES) ? dst_at(ei, idx, i32) : (idx - EDGES);
    atomicAdd(&cnt[d], 1);
}

// multiblock scan: scan1 (block sums) -> scan2 (scan of 196 sums) -> scan3 (apply)
__global__ __launch_bounds__(256) void scan1_kernel(const int* __restrict__ cnt,
                                                    int* __restrict__ bsum) {
    int i = blockIdx.x * 256 + threadIdx.x;
    int v = (i < NN) ? cnt[i] : 0;
#pragma unroll
    for (int off = 32; off >= 1; off >>= 1) v += __shfl_xor(v, off);
    __shared__ int ws[4];
    if ((threadIdx.x & 63) == 0) ws[threadIdx.x >> 6] = v;
    __syncthreads();
    if (threadIdx.x == 0) bsum[blockIdx.x] = ws[0] + ws[1] + ws[2] + ws[3];
}

__global__ __launch_bounds__(256) void scan2_kernel(const int* __restrict__ bsum,
                                                    int* __restrict__ boff,
                                                    int* __restrict__ rowptrN) {
    __shared__ int sm[256];
    int t = threadIdx.x;
    int v = (t < SCAN_B) ? bsum[t] : 0;
    sm[t] = v;
    __syncthreads();
    for (int off = 1; off < 256; off <<= 1) {
        int x = (t >= off) ? sm[t - off] : 0;
        __syncthreads();
        sm[t] += x;
        __syncthreads();
    }
    if (t < SCAN_B) boff[t] = sm[t] - v;   // exclusive prefix
    if (t == 255) *rowptrN = sm[255];      // total (== ETOT)
}

__global__ __launch_bounds__(256) void scan3_kernel(const int* __restrict__ cnt,
                                                    const int* __restrict__ boff,
                                                    int* __restrict__ rowptr,
                                                    int* __restrict__ cursor) {
    __shared__ int sm[256];
    int t = threadIdx.x;
    int i = blockIdx.x * 256 + t;
    int v = (i < NN) ? cnt[i] : 0;
    sm[t] = v;
    __syncthreads();
    for (int off = 1; off < 256; off <<= 1) {
        int x = (t >= off) ? sm[t - off] : 0;
        __syncthreads();
        sm[t] += x;
        __syncthreads();
    }
    if (i < NN) {
        int excl = boff[blockIdx.x] + sm[t] - v;
        rowptr[i] = excl;
        cursor[i] = excl;
    }
}

__global__ void scatter_kernel(const int* __restrict__ ei, const int* __restrict__ flag,
                               int* __restrict__ cursor, int* __restrict__ colidx) {
    int idx = blockIdx.x * blockDim.x + threadIdx.x;
    if (idx >= ETOT) return;
    bool i32 = (*flag != 0);
    int s, d;
    if (idx < EDGES) { s = src_at(ei, idx, i32); d = dst_at(ei, idx, i32); }
    else { s = d = idx - EDGES; }
    int pos = atomicAdd(&cursor[d], 1);
    colidx[pos] = s;
}

// ---------------- generic GEMM (only for K=39 encoder-1) ----------------
template <int NC, bool RELU>
__global__ __launch_bounds__(256) void gemm_small_kernel(const float* __restrict__ A,
                                                         const float* __restrict__ B,
                                                         const float* __restrict__ bias,
                                                         float* __restrict__ C, int M, int K) {
    constexpr int TM = 32;
    constexpr int GROUPS = 256 / NC;
    constexpr int RPG = TM / GROUPS;
    constexpr int KC = 64;
    __shared__ float As[TM * 128];
    __shared__ float Bs[KC * NC];
    int t = threadIdx.x;
    int i0 = blockIdx.x * TM;

    int rows = M - i0; if (rows > TM) rows = TM;
    for (int idx = t; idx < rows * K; idx += 256) {
        int r = idx / K, k = idx - r * K;
        As[r * K + k] = A[(size_t)(i0 + r) * K + k];
    }

    int col = t % NC, grp = t / NC;
    int rg0 = grp * RPG;
    float acc[RPG];
#pragma unroll
    for (int r = 0; r < RPG; ++r) acc[r] = 0.f;

    for (int k0 = 0; k0 < K; k0 += KC) {
        int kc = K - k0; if (kc > KC) kc = KC;
        __syncthreads();
        for (int idx = t; idx < kc * NC; idx += 256) Bs[idx] = B[(size_t)k0 * NC + idx];
        __syncthreads();
        for (int k = 0; k < kc; ++k) {
            float bv = Bs[k * NC + col];
#pragma unroll
            for (int r = 0; r < RPG; ++r) acc[r] += As[(rg0 + r) * K + k0 + k] * bv;
        }
    }

    float bb = bias ? bias[col] : 0.f;
#pragma unroll
    for (int r = 0; r < RPG; ++r) {
        int i = i0 + rg0 + r;
        if (i < M) {
            float v = acc[r] + bb;
            if (RELU) v = v > 0.f ? v : 0.f;
            C[(size_t)i * NC + col] = v;
        }
    }
}

// ---------------- fast GEMM: C[M,128] = act(A[M,128] @ B[128,128] + bias) ----------------
template <bool RELU>
__global__ __launch_bounds__(256) void gemm128_kernel(const float* __restrict__ A,
                                                      const float* __restrict__ B,
                                                      const float* __restrict__ bias,
                                                      float* __restrict__ C, int M) {
    __shared__ float As[64 * 128];   // 32 KB, full K
    __shared__ float Bs[64 * 128];   // 32 KB, K-chunk
    int t = threadIdx.x;
    int i0 = blockIdx.x * 64;
    int tc = t & 31;                 // cols: tc + 32j
    int tr = t >> 5;
    int r0 = tr * 8;

    for (int idx = t * 4; idx < 64 * 128; idx += 1024) {
        int r = idx >> 7, k = idx & 127;
        float4 v4 = make_float4(0.f, 0.f, 0.f, 0.f);
        if (i0 + r < M) v4 = *(const float4*)&A[(size_t)(i0 + r) * 128 + k];
        *(float4*)&As[idx] = v4;
    }

    float acc[8][4];
#pragma unroll
    for (int i = 0; i < 8; ++i)
#pragma unroll
        for (int j = 0; j < 4; ++j) acc[i][j] = 0.f;

    for (int k0 = 0; k0 < 128; k0 += 64) {
        __syncthreads();
        for (int idx = t * 4; idx < 64 * 128; idx += 1024)
            *(float4*)&Bs[idx] = *(const float4*)&B[(size_t)k0 * 128 + idx];
        __syncthreads();
#pragma unroll 4
        for (int k = 0; k < 64; k += 4) {
            float4 a4[8];
#pragma unroll
            for (int i = 0; i < 8; ++i)
                a4[i] = *(const float4*)&As[(r0 + i) * 128 + k0 + k];
            float bb[4][4];
#pragma unroll
            for (int kk = 0; kk < 4; ++kk)
#pragma unroll
                for (int j = 0; j < 4; ++j)
                    bb[kk][j] = Bs[(k + kk) * 128 + tc + 32 * j];
#pragma unroll
            for (int i = 0; i < 8; ++i) {
                const float* av = (const float*)&a4[i];
#pragma unroll
                for (int kk = 0; kk < 4; ++kk)
#pragma unroll
                    for (int j = 0; j < 4; ++j)
                        acc[i][j] += av[kk] * bb[kk][j];
            }
        }
    }

#pragma unroll
    for (int i = 0; i < 8; ++i) {
        int row = i0 + r0 + i;
        if (row < M) {
#pragma unroll
            for (int j = 0; j < 4; ++j) {
                int col = tc + 32 * j;
                float v = acc[i][j] + (bias ? bias[col] : 0.f);
                if (RELU) v = v > 0.f ? v : 0.f;
                C[(size_t)row * 128 + col] = v;
            }
        }
    }
}

// ---------------- merged head GEMMs ----------------
__global__ __launch_bounds__(256) void gemm_heads_kernel(const float* __restrict__ A,
                                                         const float* __restrict__ iw1,
                                                         const float* __restrict__ ib1,
                                                         const float* __restrict__ tw1,
                                                         const float* __restrict__ tb1,
                                                         float* __restrict__ imp1,
                                                         float* __restrict__ tim1, int M) {
    __shared__ float As[64 * 128];
    __shared__ float Bs[64 * 128];
    int t = threadIdx.x;
    int i0 = blockIdx.x * 64;
    int tc = t & 31;
    int tr = t >> 5;
    int r0 = tr * 8;

    for (int idx = t * 4; idx < 64 * 128; idx += 1024) {
        int r = idx >> 7, k = idx & 127;
        float4 v4 = make_float4(0.f, 0.f, 0.f, 0.f);
        if (i0 + r < M) v4 = *(const float4*)&A[(size_t)(i0 + r) * 128 + k];
        *(float4*)&As[idx] = v4;
    }

    float acc[8][4];
#pragma unroll
    for (int i = 0; i < 8; ++i)
#pragma unroll
        for (int j = 0; j < 4; ++j) acc[i][j] = 0.f;

    for (int k0 = 0; k0 < 128; k0 += 64) {
        __syncthreads();
        for (int idx = t * 4; idx < 64 * 128; idx += 1024) {
            int k = idx >> 7, cl = idx & 127;
            float4 v4 = (cl < 64)
                ? *(const float4*)&iw1[(size_t)(k0 + k) * 64 + cl]
                : *(const float4*)&tw1[(size_t)(k0 + k) * 64 + (cl - 64)];
            *(float4*)&Bs[idx] = v4;
        }
        __syncthreads();
#pragma unroll 4
        for (int k = 0; k < 64; k += 4) {
            float4 a4[8];
#pragma unroll
            for (int i = 0; i < 8; ++i)
                a4[i] = *(const float4*)&As[(r0 + i) * 128 + k0 + k];
            float bb[4][4];
#pragma unroll
            for (int kk = 0; kk < 4; ++kk)
#pragma unroll
                for (int j = 0; j < 4; ++j)
                    bb[kk][j] = Bs[(k + kk) * 128 + tc + 32 * j];
#pragma unroll
            for (int i = 0; i < 8; ++i) {
                const float* av = (const float*)&a4[i];
#pragma unroll
                for (int kk = 0; kk < 4; ++kk)
#pragma unroll
                    for (int j = 0; j < 4; ++j)
                        acc[i][j] += av[kk] * bb[kk][j];
            }
        }
    }

#pragma unroll
    for (int i = 0; i < 8; ++i) {
        int row = i0 + r0 + i;
        if (row < M) {
#pragma unroll
            for (int j = 0; j < 4; ++j) {
                int col = tc + 32 * j;
                float b = (col < 64) ? ib1[col] : tb1[col - 64];
                float v = acc[i][j] + b;
                v = v > 0.f ? v : 0.f;
                if (col < 64) imp1[(size_t)row * 64 + col] = v;
                else          tim1[(size_t)row * 64 + (col - 64)] = v;
            }
        }
    }
}

// ---------------- es/ed: coalesced, block = 2 nodes, 32-lane shuffle reduce ----------------
__global__ __launch_bounds__(256) void attn_prep_kernel(const float* __restrict__ xp,
                                                        const float* __restrict__ a_s,
                                                        const float* __restrict__ a_d,
                                                        float* __restrict__ es,
                                                        float* __restrict__ ed) {
    int t = threadIdx.x;
    int i = blockIdx.x * 2 + (t >> 7);
    int c = t & 127;
    float v = xp[(size_t)i * 128 + c];
    float ps = v * a_s[c];
    float pd = v * a_d[c];
#pragma unroll
    for (int off = 16; off >= 1; off >>= 1) {
        ps += __shfl_xor(ps, off);
        pd += __shfl_xor(pd, off);
    }
    if ((c & 31) == 0) {
        es[i * 4 + (c >> 5)] = ps;
        ed[i * 4 + (c >> 5)] = pd;
    }
}

// ---------------- gat v3: one wave per node, barrier-free, shfl redistribution ----------------
__global__ __launch_bounds__(256) void gat_agg_ln_kernel(
    const float* __restrict__ xp, const float* __restrict__ es, const float* __restrict__ ed,
    const int* __restrict__ rowptr, const int* __restrict__ colidx,
    const float* __restrict__ h_in,
    const float* __restrict__ bc, const float* __restrict__ g, const float* __restrict__ be,
    float* __restrict__ h_out) {
    int wv = threadIdx.x >> 6;
    int l  = threadIdx.x & 63;
    int v  = blockIdx.x * 4 + wv;
    if (v >= NN) return;
    int s0 = rowptr[v], s1 = rowptr[v + 1];
    int h0 = l >> 5;                       // lane's head for c0=l; c1=l+64 has head 2+h0
    float edp = ed[v * 4 + (l & 3)];       // phase-1: lane computes head (l&3)

    float acc0 = 0.f, acc1 = 0.f, den0 = 0.f, den1 = 0.f;
    for (int p0 = s0; p0 < s1; p0 += 16) {
        int n = s1 - p0; if (n > 16) n = 16;
        // phase 1: lanes 0..4n-1 compute w for (edge l>>2, head l&3); u held in lane group
        int e = l >> 2;
        int ureg = 0;
        float wreg = 0.f;
        if (e < n) {
            ureg = colidx[p0 + e];
            float tt = es[ureg * 4 + (l & 3)] + edp;
            tt = tt > 0.f ? tt : 0.2f * tt;
            wreg = __expf(tt);             // no max-shift: |e| small, softmax shift-invariant
        }
        // phase 2: redistribute via shfl, accumulate
        for (int e2 = 0; e2 < n; ++e2) {
            int u = __shfl(ureg, e2 * 4);
            float w0 = __shfl(wreg, e2 * 4 + h0);
            float w1 = __shfl(wreg, e2 * 4 + 2 + h0);
            const float* xr = xp + (size_t)u * 128;
            acc0 += w0 * xr[l];
            acc1 += w1 * xr[l + 64];
            den0 += w0;
            den1 += w1;
        }
    }

    float y0 = acc0 / den0 + bc[l]      + h_in[(size_t)v * 128 + l];
    float y1 = acc1 / den1 + bc[l + 64] + h_in[(size_t)v * 128 + l + 64];

    float s = y0 + y1;
#pragma unroll
    for (int off = 32; off >= 1; off >>= 1) s += __shfl_xor(s, off);
    float mean = s * (1.f / 128.f);
    float d0 = y0 - mean, d1 = y1 - mean;
    float vv = d0 * d0 + d1 * d1;
#pragma unroll
    for (int off = 32; off >= 1; off >>= 1) vv += __shfl_xor(vv, off);
    float rstd = rsqrtf(vv * (1.f / 128.f) + 1e-5f);
    float z0 = d0 * rstd * g[l] + be[l];
    float z1 = d1 * rstd * g[l + 64] + be[l + 64];
    h_out[(size_t)v * 128 + l]      = z0 > 0.f ? z0 : 0.f;
    h_out[(size_t)v * 128 + l + 64] = z1 > 0.f ? z1 : 0.f;
}

// ---------------- output heads: thread-per-node, float4 row reads, LDS weights ----------------
__global__ __launch_bounds__(256) void heads_kernel(const float* __restrict__ imp1,
                                                    const float* __restrict__ tim1,
                                                    const float* __restrict__ iw2,
                                                    const float* __restrict__ ib2,
                                                    const float* __restrict__ tw2,
                                                    const float* __restrict__ tb2,
                                                    float* __restrict__ out) {
    __shared__ float wi[64 * 3], wt[64 * 2], bsh[5];
    int t = threadIdx.x;
    for (int idx = t; idx < 192; idx += 256) wi[idx] = iw2[idx];
    for (int idx = t; idx < 128; idx += 256) wt[idx] = tw2[idx];
    if (t < 3) bsh[t] = ib2[t];
    if (t < 2) bsh[3 + t] = tb2[t];
    __syncthreads();
    int i = blockIdx.x * 256 + t;
    if (i >= NN) return;
    float a0 = bsh[0], a1 = bsh[1], a2 = bsh[2], t0 = bsh[3], t1 = bsh[4];
    const float* ri = imp1 + (size_t)i * 64;
    const float* rt = tim1 + (size_t)i * 64;
#pragma unroll 4
    for (int k = 0; k < 64; k += 4) {
        float4 vi = *(const float4*)&ri[k];
        float4 vt = *(const float4*)&rt[k];
        const float* pi = (const float*)&vi;
        const float* pt = (const float*)&vt;
#pragma unroll
        for (int kk = 0; kk < 4; ++kk) {
            a0 += pi[kk] * wi[(k + kk) * 3 + 0];
            a1 += pi[kk] * wi[(k + kk) * 3 + 1];
            a2 += pi[kk] * wi[(k + kk) * 3 + 2];
            t0 += pt[kk] * wt[(k + kk) * 2 + 0];
            t1 += pt[kk] * wt[(k + kk) * 2 + 1];
        }
    }
    out[(size_t)i * 3 + 0] = a0;
    out[(size_t)i * 3 + 1] = a1;
    out[(size_t)i * 3 + 2] = a2;
    float sp0 = t0 > 20.f ? t0 : log1pf(__expf(t0));
    float sp1 = t1 > 20.f ? t1 : log1pf(__expf(t1));
    out[(size_t)(NN * 3) + (size_t)i * 2 + 0] = sp0;
    out[(size_t)(NN * 3) + (size_t)i * 2 + 1] = sp1;
}

extern "C" void kernel_launch(void* const* d_in, const int* in_sizes, int n_in,
                              void* d_out, int out_size, void* d_ws, size_t ws_size,
                              hipStream_t stream) {
    const float* x      = (const float*)d_in[0];
    const int*   ei     = (const int*)d_in[1];
    const float* enc_w1 = (const float*)d_in[2];
    const float* enc_b1 = (const float*)d_in[3];
    const float* enc_w2 = (const float*)d_in[4];
    const float* enc_b2 = (const float*)d_in[5];
    const float *W[3], *as_[3], *ad_[3], *bc[3], *g[3], *be[3];
    for (int l = 0; l < 3; ++l) {
        W[l]   = (const float*)d_in[6 + l * 6 + 0];
        as_[l] = (const float*)d_in[6 + l * 6 + 1];
        ad_[l] = (const float*)d_in[6 + l * 6 + 2];
        bc[l]  = (const float*)d_in[6 + l * 6 + 3];
        g[l]   = (const float*)d_in[6 + l * 6 + 4];
        be[l]  = (const float*)d_in[6 + l * 6 + 5];
    }
    const float* imp_w1 = (const float*)d_in[24];
    const float* imp_b1 = (const float*)d_in[25];
    const float* imp_w2 = (const float*)d_in[26];
    const float* imp_b2 = (const float*)d_in[27];
    const float* tim_w1 = (const float*)d_in[28];
    const float* tim_b1 = (const float*)d_in[29];
    const float* tim_w2 = (const float*)d_in[30];
    const float* tim_b2 = (const float*)d_in[31];

    int* flag   = (int*)d_ws;
    int* cnt    = flag + 64;
    int* cursor = cnt + NN;
    int* rowptr = cursor + NN;
    int* colidx = rowptr + (NN + 1);
    int* bsum   = colidx + ETOT;
    int* boff   = bsum + 256;
    uintptr_t fb = (uintptr_t)(boff + 256);
    fb = (fb + 255) & ~(uintptr_t)255;
    float* es = (float*)fb;
    float* ed = es + (size_t)NN * 4;
    float* hA = ed + (size_t)NN * 4;
    float* hB = hA + (size_t)NN * 128;
    float* xp = hB + (size_t)NN * 128;
    float* tmp = xp;   // aliased: tmp dead before xp lives, and vice versa

    hipMemsetAsync(flag, 0, sizeof(int), stream);
    hipMemsetAsync(cnt, 0, NN * sizeof(int), stream);
    detect_kernel<<<16, 256, 0, stream>>>(ei, flag);
    hist_kernel<<<(ETOT + 255) / 256, 256, 0, stream>>>(ei, flag, cnt);
    scan1_kernel<<<SCAN_B, 256, 0, stream>>>(cnt, bsum);
    scan2_kernel<<<1, 256, 0, stream>>>(bsum, boff, rowptr + NN);
    scan3_kernel<<<SCAN_B, 256, 0, stream>>>(cnt, boff, rowptr, cursor);
    scatter_kernel<<<(ETOT + 255) / 256, 256, 0, stream>>>(ei, flag, cursor, colidx);

    const int GB64 = (NN + 63) / 64;
    gemm_small_kernel<128, true><<<(NN + 31) / 32, 256, 0, stream>>>(x, enc_w1, enc_b1, tmp, NN, FINDIM);
    gemm128_kernel<false><<<GB64, 256, 0, stream>>>(tmp, enc_w2, enc_b2, hA, NN);

    float* hcur = hA;
    float* hnext = hB;
    for (int l = 0; l < 3; ++l) {
        gemm128_kernel<false><<<GB64, 256, 0, stream>>>(hcur, W[l], nullptr, xp, NN);
        attn_prep_kernel<<<NN / 2, 256, 0, stream>>>(xp, as_[l], ad_[l], es, ed);
        gat_agg_ln_kernel<<<(NN + 3) / 4, 256, 0, stream>>>(xp, es, ed, rowptr, colidx, hcur,
                                                            bc[l], g[l], be[l], hnext);
        float* t2 = hcur; hcur = hnext; hnext = t2;
    }

    float* imp1 = tmp;
    float* tim1 = tmp + (size_t)NN * 64;
    gemm_heads_kernel<<<GB64, 256, 0, stream>>>(hcur, imp_w1, imp_b1, tim_w1, tim_b1,
                                                imp1, tim1, NN);
    heads_kernel<<<(NN + 255) / 256, 256, 0, stream>>>(imp1, tim1, imp_w2, imp_b2,
                                                       tim_w2, tim_b2, (float*)d_out);
}

// Round 9
// 858.229 us; speedup vs baseline: 1.9690x; 1.1682x over previous
//
#include <hip/hip_runtime.h>
#include <hip/hip_bf16.h>
#include <math.h>

#define NN 50000
#define EDGES 1600000
#define ETOT (EDGES + NN)
#define FINDIM 39
#define NPART 128
#define PSZ 391        // dsts per partition; 128*391 = 50048 >= NN
#define PCAP 14000     // capacity per partition (avg 12891, +9.8 sigma)
#define P1TILE 4096

// ---------------- edge_index dtype sniffer (int64 safety net) ----------------
__global__ void detect_kernel(const int* __restrict__ ei, int* __restrict__ flag) {
    int t = blockIdx.x * blockDim.x + threadIdx.x;   // 4096 threads
    if (ei[2 * t + 1] != 0) atomicOr(flag, 1);       // flag=1 -> int32
}

__device__ __forceinline__ int src_at(const int* ei, int i, bool i32) {
    return i32 ? ei[i] : ei[2 * i];
}
__device__ __forceinline__ int dst_at(const int* ei, int i, bool i32) {
    return i32 ? ei[EDGES + i] : ei[2 * (EDGES + i)];
}

// ---------------- CSR pass 1: bucket edges into 128 dst-range partitions ----------------
__global__ __launch_bounds__(256) void pass1_kernel(const int* __restrict__ ei,
                                                    const int* __restrict__ flag,
                                                    int* __restrict__ gcursor,
                                                    unsigned* __restrict__ pbuf) {
    __shared__ unsigned raw[P1TILE];
    __shared__ unsigned srt[P1TILE];
    __shared__ int pcnt[NPART], poff[NPART], pcur[NPART], gb[NPART];
    bool i32 = (*flag != 0);
    int chunk = (ETOT + gridDim.x - 1) / gridDim.x;
    int c0 = blockIdx.x * chunk;
    int c1 = c0 + chunk; if (c1 > ETOT) c1 = ETOT;
    int t = threadIdx.x;
    for (int t0 = c0; t0 < c1; t0 += P1TILE) {
        int tn = c1 - t0; if (tn > P1TILE) tn = P1TILE;
        if (t < NPART) { pcnt[t] = 0; pcur[t] = 0; }
        __syncthreads();
        for (int i = t; i < tn; i += 256) {
            int e = t0 + i;
            int s, d;
            if (e < EDGES) { s = src_at(ei, e, i32); d = dst_at(ei, e, i32); }
            else { s = d = e - EDGES; }
            raw[i] = ((unsigned)s << 16) | (unsigned)d;
            atomicAdd(&pcnt[d / PSZ], 1);
        }
        __syncthreads();
        if (t < NPART) poff[t] = pcnt[t];
        __syncthreads();
        for (int off = 1; off < NPART; off <<= 1) {
            int v = 0;
            if (t < NPART && t >= off) v = poff[t - off];
            __syncthreads();
            if (t < NPART) poff[t] += v;
            __syncthreads();
        }
        if (t < NPART) {
            poff[t] -= pcnt[t];                       // exclusive
            gb[t] = atomicAdd(&gcursor[t], pcnt[t]);  // global base for this tile's run
        }
        __syncthreads();
        for (int i = t; i < tn; i += 256) {
            unsigned r = raw[i];
            int part = (int)(r & 0xFFFFu) / PSZ;
            int pos = poff[part] + atomicAdd(&pcur[part], 1);
            srt[pos] = r;
        }
        __syncthreads();
        for (int i = t; i < tn; i += 256) {
            unsigned r = srt[i];
            int part = (int)(r & 0xFFFFu) / PSZ;
            int gpos = gb[part] + (i - poff[part]);
            if (gpos < PCAP) pbuf[(size_t)part * PCAP + gpos] = r;
        }
        __syncthreads();
    }
}

// ---------------- CSR: scan 128 partition totals ----------------
__global__ __launch_bounds__(128) void scan_part_kernel(const int* __restrict__ gcursor,
                                                        int* __restrict__ pbase,
                                                        int* __restrict__ rowptrN) {
    __shared__ int sm[NPART];
    int t = threadIdx.x;
    int v = gcursor[t];
    sm[t] = v;
    __syncthreads();
    for (int off = 1; off < NPART; off <<= 1) {
        int x = (t >= off) ? sm[t - off] : 0;
        __syncthreads();
        sm[t] += x;
        __syncthreads();
    }
    pbase[t] = sm[t] - v;
    if (t == NPART - 1) *rowptrN = sm[t];   // == ETOT
}

// ---------------- CSR pass 2: per-partition exact sort -> rowptr + colidx ----------------
__global__ __launch_bounds__(256) void pass2_kernel(const unsigned* __restrict__ pbuf,
                                                    const int* __restrict__ gcursor,
                                                    const int* __restrict__ pbase,
                                                    int* __restrict__ rowptr,
                                                    int* __restrict__ colidx) {
    __shared__ unsigned recs[PCAP];                 // 56 KB
    __shared__ int lhist[PSZ], lexcl[PSZ], lcur[PSZ];
    int p = blockIdx.x;
    int t = threadIdx.x;
    int n = gcursor[p]; if (n > PCAP) n = PCAP;
    int base = pbase[p];
    int d0 = p * PSZ;
    int nd = NN - d0; if (nd > PSZ) nd = PSZ;
    for (int i = t; i < nd; i += 256) { lhist[i] = 0; lcur[i] = 0; }
    __syncthreads();
    for (int i = t; i < n; i += 256) {
        unsigned r = pbuf[(size_t)p * PCAP + i];
        recs[i] = r;
        atomicAdd(&lhist[(int)(r & 0xFFFFu) - d0], 1);
    }
    __syncthreads();
    for (int i = t; i < nd; i += 256) lexcl[i] = lhist[i];
    __syncthreads();
    for (int off = 1; off < PSZ; off <<= 1) {
        int a0 = 0, a1 = 0;
        int i0 = t, i1 = t + 256;
        if (i0 < nd && i0 >= off) a0 = lexcl[i0 - off];
        if (i1 < nd && i1 >= off) a1 = lexcl[i1 - off];
        __syncthreads();
        if (i0 < nd) lexcl[i0] += a0;
        if (i1 < nd) lexcl[i1] += a1;
        __syncthreads();
    }
    for (int i = t; i < nd; i += 256) {
        lexcl[i] -= lhist[i];                        // exclusive
        rowptr[d0 + i] = base + lexcl[i];
    }
    __syncthreads();
    for (int i = t; i < n; i += 256) {
        unsigned r = recs[i];
        int li = (int)(r & 0xFFFFu) - d0;
        int pos = base + lexcl[li] + atomicAdd(&lcur[li], 1);
        colidx[pos] = (int)(r >> 16);
    }
}

// ---------------- generic GEMM (K=39 encoder-1 only) ----------------
template <int NC, bool RELU>
__global__ __launch_bounds__(256) void gemm_small_kernel(const float* __restrict__ A,
                                                         const float* __restrict__ B,
                                                         const float* __restrict__ bias,
                                                         float* __restrict__ C, int M, int K) {
    constexpr int TM = 32;
    constexpr int GROUPS = 256 / NC;
    constexpr int RPG = TM / GROUPS;
    constexpr int KC = 64;
    __shared__ float As[TM * 128];
    __shared__ float Bs[KC * NC];
    int t = threadIdx.x;
    int i0 = blockIdx.x * TM;

    int rows = M - i0; if (rows > TM) rows = TM;
    for (int idx = t; idx < rows * K; idx += 256) {
        int r = idx / K, k = idx - r * K;
        As[r * K + k] = A[(size_t)(i0 + r) * K + k];
    }

    int col = t % NC, grp = t / NC;
    int rg0 = grp * RPG;
    float acc[RPG];
#pragma unroll
    for (int r = 0; r < RPG; ++r) acc[r] = 0.f;

    for (int k0 = 0; k0 < K; k0 += KC) {
        int kc = K - k0; if (kc > KC) kc = KC;
        __syncthreads();
        for (int idx = t; idx < kc * NC; idx += 256) Bs[idx] = B[(size_t)k0 * NC + idx];
        __syncthreads();
        for (int k = 0; k < kc; ++k) {
            float bv = Bs[k * NC + col];
#pragma unroll
            for (int r = 0; r < RPG; ++r) acc[r] += As[(rg0 + r) * K + k0 + k] * bv;
        }
    }

    float bb = bias ? bias[col] : 0.f;
#pragma unroll
    for (int r = 0; r < RPG; ++r) {
        int i = i0 + rg0 + r;
        if (i < M) {
            float v = acc[r] + bb;
            if (RELU) v = v > 0.f ? v : 0.f;
            C[(size_t)i * NC + col] = v;
        }
    }
}

// ---------------- fast GEMM 128x128 (+ optional fused es/ed epilogue) ----------------
template <bool BIAS, bool EPI>
__global__ __launch_bounds__(256) void gemm128_kernel(const float* __restrict__ A,
                                                      const float* __restrict__ B,
                                                      const float* __restrict__ bias,
                                                      float* __restrict__ C,
                                                      const float* __restrict__ a_s,
                                                      const float* __restrict__ a_d,
                                                      float* __restrict__ es,
                                                      float* __restrict__ ed, int M) {
    __shared__ float As[64 * 128];
    __shared__ float Bs[64 * 128];
    int t = threadIdx.x;
    int i0 = blockIdx.x * 64;
    int tc = t & 31;
    int tr = t >> 5;
    int r0 = tr * 8;

    for (int idx = t * 4; idx < 64 * 128; idx += 1024) {
        int r = idx >> 7, k = idx & 127;
        float4 v4 = make_float4(0.f, 0.f, 0.f, 0.f);
        if (i0 + r < M) v4 = *(const float4*)&A[(size_t)(i0 + r) * 128 + k];
        *(float4*)&As[idx] = v4;
    }

    float acc[8][4];
#pragma unroll
    for (int i = 0; i < 8; ++i)
#pragma unroll
        for (int j = 0; j < 4; ++j) acc[i][j] = 0.f;

    for (int k0 = 0; k0 < 128; k0 += 64) {
        __syncthreads();
        for (int idx = t * 4; idx < 64 * 128; idx += 1024)
            *(float4*)&Bs[idx] = *(const float4*)&B[(size_t)k0 * 128 + idx];
        __syncthreads();
#pragma unroll 4
        for (int k = 0; k < 64; k += 4) {
            float4 a4[8];
#pragma unroll
            for (int i = 0; i < 8; ++i)
                a4[i] = *(const float4*)&As[(r0 + i) * 128 + k0 + k];
            float bb[4][4];
#pragma unroll
            for (int kk = 0; kk < 4; ++kk)
#pragma unroll
                for (int j = 0; j < 4; ++j)
                    bb[kk][j] = Bs[(k + kk) * 128 + tc + 32 * j];
#pragma unroll
            for (int i = 0; i < 8; ++i) {
                const float* av = (const float*)&a4[i];
#pragma unroll
                for (int kk = 0; kk < 4; ++kk)
#pragma unroll
                    for (int j = 0; j < 4; ++j)
                        acc[i][j] += av[kk] * bb[kk][j];
            }
        }
    }

#pragma unroll
    for (int i = 0; i < 8; ++i) {
        int row = i0 + r0 + i;
        if (row < M) {
#pragma unroll
            for (int j = 0; j < 4; ++j) {
                int col = tc + 32 * j;
                float v = acc[i][j] + (BIAS ? bias[col] : 0.f);
                C[(size_t)row * 128 + col] = v;
            }
        }
    }

    if (EPI) {
        // es[row][j] = sum_tc acc[i][j]*a_s[32j+tc]; reduce across the 32 tc-lanes
#pragma unroll
        for (int i = 0; i < 8; ++i) {
            int row = i0 + r0 + i;
#pragma unroll
            for (int j = 0; j < 4; ++j) {
                float s = acc[i][j] * a_s[32 * j + tc];
                float d = acc[i][j] * a_d[32 * j + tc];
#pragma unroll
                for (int off = 16; off >= 1; off >>= 1) {
                    s += __shfl_xor(s, off);
                    d += __shfl_xor(d, off);
                }
                if (tc == 0 && row < M) {
                    es[row * 4 + j] = s;
                    ed[row * 4 + j] = d;
                }
            }
        }
    }
}

// ---------------- head GEMMs fully fused: h -> out (impact+timing) ----------------
__global__ __launch_bounds__(256) void gemm_heads_kernel(const float* __restrict__ A,
                                                         const float* __restrict__ iw1,
                                                         const float* __restrict__ ib1,
                                                         const float* __restrict__ tw1,
                                                         const float* __restrict__ tb1,
                                                         const float* __restrict__ iw2,
                                                         const float* __restrict__ ib2,
                                                         const float* __restrict__ tw2,
                                                         const float* __restrict__ tb2,
                                                         float* __restrict__ out, int M) {
    __shared__ float As[64 * 128];
    __shared__ float Bs[64 * 128];
    int t = threadIdx.x;
    int i0 = blockIdx.x * 64;
    int tc = t & 31;
    int tr = t >> 5;
    int r0 = tr * 8;

    for (int idx = t * 4; idx < 64 * 128; idx += 1024) {
        int r = idx >> 7, k = idx & 127;
        float4 v4 = make_float4(0.f, 0.f, 0.f, 0.f);
        if (i0 + r < M) v4 = *(const float4*)&A[(size_t)(i0 + r) * 128 + k];
        *(float4*)&As[idx] = v4;
    }

    float acc[8][4];
#pragma unroll
    for (int i = 0; i < 8; ++i)
#pragma unroll
        for (int j = 0; j < 4; ++j) acc[i][j] = 0.f;

    for (int k0 = 0; k0 < 128; k0 += 64) {
        __syncthreads();
        for (int idx = t * 4; idx < 64 * 128; idx += 1024) {
            int k = idx >> 7, cl = idx & 127;
            float4 v4 = (cl < 64)
                ? *(const float4*)&iw1[(size_t)(k0 + k) * 64 + cl]
                : *(const float4*)&tw1[(size_t)(k0 + k) * 64 + (cl - 64)];
            *(float4*)&Bs[idx] = v4;
        }
        __syncthreads();
#pragma unroll 4
        for (int k = 0; k < 64; k += 4) {
            float4 a4[8];
#pragma unroll
            for (int i = 0; i < 8; ++i)
                a4[i] = *(const float4*)&As[(r0 + i) * 128 + k0 + k];
            float bb[4][4];
#pragma unroll
            for (int kk = 0; kk < 4; ++kk)
#pragma unroll
                for (int j = 0; j < 4; ++j)
                    bb[kk][j] = Bs[(k + kk) * 128 + tc + 32 * j];
#pragma unroll
            for (int i = 0; i < 8; ++i) {
                const float* av = (const float*)&a4[i];
#pragma unroll
                for (int kk = 0; kk < 4; ++kk)
#pragma unroll
                    for (int j = 0; j < 4; ++j)
                        acc[i][j] += av[kk] * bb[kk][j];
            }
        }
    }

    // epilogue: relu(acc + b1), then tiny second-layer matmuls reduced across tc-lanes
    float v[8][4];
#pragma unroll
    for (int i = 0; i < 8; ++i)
#pragma unroll
        for (int j = 0; j < 4; ++j) {
            int col = tc + 32 * j;
            float b = (col < 64) ? ib1[col] : tb1[col - 64];
            float x = acc[i][j] + b;
            v[i][j] = x > 0.f ? x : 0.f;
        }
#pragma unroll
    for (int i = 0; i < 8; ++i) {
        int row = i0 + r0 + i;
#pragma unroll
        for (int c = 0; c < 3; ++c) {
            float pc = v[i][0] * iw2[tc * 3 + c] + v[i][1] * iw2[(32 + tc) * 3 + c];
#pragma unroll
            for (int off = 16; off >= 1; off >>= 1) pc += __shfl_xor(pc, off);
            if (tc == 0 && row < M) out[(size_t)row * 3 + c] = pc + ib2[c];
        }
#pragma unroll
        for (int d = 0; d < 2; ++d) {
            float pd = v[i][2] * tw2[tc * 2 + d] + v[i][3] * tw2[(32 + tc) * 2 + d];
#pragma unroll
            for (int off = 16; off >= 1; off >>= 1) pd += __shfl_xor(pd, off);
            if (tc == 0 && row < M) {
                float a = pd + tb2[d];
                float sp = a > 20.f ? a : log1pf(__expf(a));
                out[(size_t)(NN * 3) + (size_t)row * 2 + d] = sp;
            }
        }
    }
}

// ---------------- edge weights: wave per node; wn[p][h] + rden[v][h] ----------------
__global__ __launch_bounds__(256) void edge_w_kernel(const float* __restrict__ es,
                                                     const float* __restrict__ ed,
                                                     const int* __restrict__ rowptr,
                                                     const int* __restrict__ colidx,
                                                     float* __restrict__ wn,
                                                     float* __restrict__ rden) {
    int wv = threadIdx.x >> 6, l = threadIdx.x & 63;
    int v = blockIdx.x * 4 + wv;
    if (v >= NN) return;
    int s0 = rowptr[v], s1 = rowptr[v + 1];
    int q = l & 3;
    float edq = ed[v * 4 + q];
    int slots = (s1 - s0) * 4;
    float den = 0.f;
    for (int idx = l; idx < slots; idx += 64) {
        int u = colidx[s0 + (idx >> 2)];
        float e = es[u * 4 + q] + edq;
        e = e > 0.f ? e : 0.2f * e;
        float w = __expf(e);       // max-shift dropped: |e| small, softmax shift-invariant
        wn[(size_t)s0 * 4 + idx] = w;
        den += w;
    }
#pragma unroll
    for (int off = 4; off < 64; off <<= 1) den += __shfl_xor(den, off);
    if (l < 4) rden[v * 4 + l] = 1.f / den;
}

// ---------------- gat v5: wave per node, lane owns channels (2l,2l+1) [same head] ----------------
__global__ __launch_bounds__(256) void gat_kernel(const float* __restrict__ xp,
                                                  const float* __restrict__ wn,
                                                  const float* __restrict__ rden,
                                                  const int* __restrict__ rowptr,
                                                  const int* __restrict__ colidx,
                                                  float* __restrict__ h,   // in-out (residual)
                                                  const float* __restrict__ bc,
                                                  const float* __restrict__ g,
                                                  const float* __restrict__ be) {
    int wv = threadIdx.x >> 6, l = threadIdx.x & 63;
    int v = blockIdx.x * 4 + wv;
    if (v >= NN) return;
    int s0 = rowptr[v], s1 = rowptr[v + 1];
    int hd = l >> 4;
    float rd = rden[v * 4 + hd];
    float ax = 0.f, ay = 0.f;
    int p = s0;
    for (; p + 4 <= s1; p += 4) {
        int u0 = colidx[p], u1 = colidx[p + 1], u2 = colidx[p + 2], u3 = colidx[p + 3];
        float w0 = wn[(size_t)(p + 0) * 4 + hd];
        float w1 = wn[(size_t)(p + 1) * 4 + hd];
        float w2 = wn[(size_t)(p + 2) * 4 + hd];
        float w3 = wn[(size_t)(p + 3) * 4 + hd];
        float2 x0 = *(const float2*)&xp[(size_t)u0 * 128 + 2 * l];
        float2 x1 = *(const float2*)&xp[(size_t)u1 * 128 + 2 * l];
        float2 x2 = *(const float2*)&xp[(size_t)u2 * 128 + 2 * l];
        float2 x3 = *(const float2*)&xp[(size_t)u3 * 128 + 2 * l];
        ax += w0 * x0.x; ay += w0 * x0.y;
        ax += w1 * x1.x; ay += w1 * x1.y;
        ax += w2 * x2.x; ay += w2 * x2.y;
        ax += w3 * x3.x; ay += w3 * x3.y;
    }
    for (; p < s1; ++p) {
        int u = colidx[p];
        float w = wn[(size_t)p * 4 + hd];
        float2 x = *(const float2*)&xp[(size_t)u * 128 + 2 * l];
        ax += w * x.x; ay += w * x.y;
    }

    float2 h2  = *(const float2*)&h[(size_t)v * 128 + 2 * l];
    float2 bc2 = *(const float2*)&bc[2 * l];
    float y0 = ax * rd + bc2.x + h2.x;
    float y1 = ay * rd + bc2.y + h2.y;

    float s = y0 + y1;
#pragma unroll
    for (int off = 32; off >= 1; off >>= 1) s += __shfl_xor(s, off);
    float mean = s * (1.f / 128.f);
    float d0 = y0 - mean, d1 = y1 - mean;
    float vv = d0 * d0 + d1 * d1;
#pragma unroll
    for (int off = 32; off >= 1; off >>= 1) vv += __shfl_xor(vv, off);
    float rstd = rsqrtf(vv * (1.f / 128.f) + 1e-5f);
    float2 g2  = *(const float2*)&g[2 * l];
    float2 be2 = *(const float2*)&be[2 * l];
    float z0 = d0 * rstd * g2.x + be2.x;
    float z1 = d1 * rstd * g2.y + be2.y;
    float2 o;
    o.x = z0 > 0.f ? z0 : 0.f;
    o.y = z1 > 0.f ? z1 : 0.f;
    *(float2*)&h[(size_t)v * 128 + 2 * l] = o;
}

extern "C" void kernel_launch(void* const* d_in, const int* in_sizes, int n_in,
                              void* d_out, int out_size, void* d_ws, size_t ws_size,
                              hipStream_t stream) {
    const float* x      = (const float*)d_in[0];
    const int*   ei     = (const int*)d_in[1];
    const float* enc_w1 = (const float*)d_in[2];
    const float* enc_b1 = (const float*)d_in[3];
    const float* enc_w2 = (const float*)d_in[4];
    const float* enc_b2 = (const float*)d_in[5];
    const float *W[3], *as_[3], *ad_[3], *bc[3], *g[3], *be[3];
    for (int l = 0; l < 3; ++l) {
        W[l]   = (const float*)d_in[6 + l * 6 + 0];
        as_[l] = (const float*)d_in[6 + l * 6 + 1];
        ad_[l] = (const float*)d_in[6 + l * 6 + 2];
        bc[l]  = (const float*)d_in[6 + l * 6 + 3];
        g[l]   = (const float*)d_in[6 + l * 6 + 4];
        be[l]  = (const float*)d_in[6 + l * 6 + 5];
    }
    const float* imp_w1 = (const float*)d_in[24];
    const float* imp_b1 = (const float*)d_in[25];
    const float* imp_w2 = (const float*)d_in[26];
    const float* imp_b2 = (const float*)d_in[27];
    const float* tim_w1 = (const float*)d_in[28];
    const float* tim_b1 = (const float*)d_in[29];
    const float* tim_w2 = (const float*)d_in[30];
    const float* tim_b2 = (const float*)d_in[31];

    int* flag    = (int*)d_ws;               // 64 ints
    int* gcursor = flag + 64;                // NPART
    int* pbase   = gcursor + NPART;          // NPART + pad
    int* rowptr  = pbase + NPART + 64;       // NN+1
    int* colidx  = rowptr + NN + 1;          // ETOT
    uintptr_t fb = (uintptr_t)(colidx + ETOT);
    fb = (fb + 255) & ~(uintptr_t)255;
    float* es   = (float*)fb;                // NN*4
    float* ed   = es + (size_t)NN * 4;       // NN*4
    float* rden = ed + (size_t)NN * 4;       // NN*4
    float* wn   = rden + (size_t)NN * 4;     // ETOT*4 (26.4 MB)
    unsigned* pbuf = (unsigned*)wn;          // NPART*PCAP aliased (dead before wn lives)
    float* h    = wn + (size_t)ETOT * 4;     // NN*128
    float* xp   = h + (size_t)NN * 128;      // NN*128
    float* tmp  = xp;                        // enc1 scratch aliases xp

    hipMemsetAsync(d_ws, 0, (64 + NPART) * sizeof(int), stream);
    detect_kernel<<<16, 256, 0, stream>>>(ei, flag);
    pass1_kernel<<<512, 256, 0, stream>>>(ei, flag, gcursor, pbuf);
    scan_part_kernel<<<1, NPART, 0, stream>>>(gcursor, pbase, rowptr + NN);
    pass2_kernel<<<NPART, 256, 0, stream>>>(pbuf, gcursor, pbase, rowptr, colidx);

    const int GB64 = (NN + 63) / 64;
    gemm_small_kernel<128, true><<<(NN + 31) / 32, 256, 0, stream>>>(x, enc_w1, enc_b1, tmp, NN, FINDIM);
    gemm128_kernel<true, false><<<GB64, 256, 0, stream>>>(tmp, enc_w2, enc_b2, h,
                                                          nullptr, nullptr, nullptr, nullptr, NN);

    for (int l = 0; l < 3; ++l) {
        gemm128_kernel<false, true><<<GB64, 256, 0, stream>>>(h, W[l], nullptr, xp,
                                                              as_[l], ad_[l], es, ed, NN);
        edge_w_kernel<<<(NN + 3) / 4, 256, 0, stream>>>(es, ed, rowptr, colidx, wn, rden);
        gat_kernel<<<(NN + 3) / 4, 256, 0, stream>>>(xp, wn, rden, rowptr, colidx, h,
                                                     bc[l], g[l], be[l]);
    }

    gemm_heads_kernel<<<GB64, 256, 0, stream>>>(h, imp_w1, imp_b1, tim_w1, tim_b1,
                                                imp_w2, imp_b2, tim_w2, tim_b2,
                                                (float*)d_out, NN);
}

// Round 10
// 830.975 us; speedup vs baseline: 2.0336x; 1.0328x over previous
//
#include <hip/hip_runtime.h>
#include <hip/hip_bf16.h>
#include <math.h>

#define NN 50000
#define EDGES 1600000
#define ETOT (EDGES + NN)
#define FINDIM 39
#define NPART 128
#define PSZ 391        // dsts per partition; 128*391 = 50048 >= NN
#define PCAP 14000     // capacity per partition (avg 12891, +9.8 sigma)
#define P1TILE 4096

// ---------------- edge_index dtype sniffer (int64 safety net) ----------------
__global__ void detect_kernel(const int* __restrict__ ei, int* __restrict__ flag) {
    int t = blockIdx.x * blockDim.x + threadIdx.x;   // 4096 threads
    if (ei[2 * t + 1] != 0) atomicOr(flag, 1);       // flag=1 -> int32
}

__device__ __forceinline__ int src_at(const int* ei, int i, bool i32) {
    return i32 ? ei[i] : ei[2 * i];
}
__device__ __forceinline__ int dst_at(const int* ei, int i, bool i32) {
    return i32 ? ei[EDGES + i] : ei[2 * (EDGES + i)];
}

// ---------------- CSR pass 1: bucket edges into 128 dst-range partitions ----------------
__global__ __launch_bounds__(256) void pass1_kernel(const int* __restrict__ ei,
                                                    const int* __restrict__ flag,
                                                    int* __restrict__ gcursor,
                                                    unsigned* __restrict__ pbuf) {
    __shared__ unsigned raw[P1TILE];
    __shared__ unsigned srt[P1TILE];
    __shared__ int pcnt[NPART], poff[NPART], pcur[NPART], gb[NPART];
    bool i32 = (*flag != 0);
    int chunk = (ETOT + gridDim.x - 1) / gridDim.x;
    int c0 = blockIdx.x * chunk;
    int c1 = c0 + chunk; if (c1 > ETOT) c1 = ETOT;
    int t = threadIdx.x;
    for (int t0 = c0; t0 < c1; t0 += P1TILE) {
        int tn = c1 - t0; if (tn > P1TILE) tn = P1TILE;
        if (t < NPART) { pcnt[t] = 0; pcur[t] = 0; }
        __syncthreads();
        for (int i = t; i < tn; i += 256) {
            int e = t0 + i;
            int s, d;
            if (e < EDGES) { s = src_at(ei, e, i32); d = dst_at(ei, e, i32); }
            else { s = d = e - EDGES; }
            raw[i] = ((unsigned)s << 16) | (unsigned)d;
            atomicAdd(&pcnt[d / PSZ], 1);
        }
        __syncthreads();
        if (t < NPART) poff[t] = pcnt[t];
        __syncthreads();
        for (int off = 1; off < NPART; off <<= 1) {
            int v = 0;
            if (t < NPART && t >= off) v = poff[t - off];
            __syncthreads();
            if (t < NPART) poff[t] += v;
            __syncthreads();
        }
        if (t < NPART) {
            poff[t] -= pcnt[t];                       // exclusive
            gb[t] = atomicAdd(&gcursor[t], pcnt[t]);  // global base for this tile's run
        }
        __syncthreads();
        for (int i = t; i < tn; i += 256) {
            unsigned r = raw[i];
            int part = (int)(r & 0xFFFFu) / PSZ;
            int pos = poff[part] + atomicAdd(&pcur[part], 1);
            srt[pos] = r;
        }
        __syncthreads();
        for (int i = t; i < tn; i += 256) {
            unsigned r = srt[i];
            int part = (int)(r & 0xFFFFu) / PSZ;
            int gpos = gb[part] + (i - poff[part]);
            if (gpos < PCAP) pbuf[(size_t)part * PCAP + gpos] = r;
        }
        __syncthreads();
    }
}

// ---------------- CSR: scan 128 partition totals ----------------
__global__ __launch_bounds__(128) void scan_part_kernel(const int* __restrict__ gcursor,
                                                        int* __restrict__ pbase,
                                                        int* __restrict__ rowptrN) {
    __shared__ int sm[NPART];
    int t = threadIdx.x;
    int v = gcursor[t];
    sm[t] = v;
    __syncthreads();
    for (int off = 1; off < NPART; off <<= 1) {
        int x = (t >= off) ? sm[t - off] : 0;
        __syncthreads();
        sm[t] += x;
        __syncthreads();
    }
    pbase[t] = sm[t] - v;
    if (t == NPART - 1) *rowptrN = sm[t];   // == ETOT
}

// ---------------- CSR pass 2: per-partition exact sort -> rowptr + colidx ----------------
__global__ __launch_bounds__(256) void pass2_kernel(const unsigned* __restrict__ pbuf,
                                                    const int* __restrict__ gcursor,
                                                    const int* __restrict__ pbase,
                                                    int* __restrict__ rowptr,
                                                    int* __restrict__ colidx) {
    __shared__ unsigned recs[PCAP];                 // 56 KB
    __shared__ int lhist[PSZ], lexcl[PSZ], lcur[PSZ];
    int p = blockIdx.x;
    int t = threadIdx.x;
    int n = gcursor[p]; if (n > PCAP) n = PCAP;
    int base = pbase[p];
    int d0 = p * PSZ;
    int nd = NN - d0; if (nd > PSZ) nd = PSZ;
    for (int i = t; i < nd; i += 256) { lhist[i] = 0; lcur[i] = 0; }
    __syncthreads();
    for (int i = t; i < n; i += 256) {
        unsigned r = pbuf[(size_t)p * PCAP + i];
        recs[i] = r;
        atomicAdd(&lhist[(int)(r & 0xFFFFu) - d0], 1);
    }
    __syncthreads();
    for (int i = t; i < nd; i += 256) lexcl[i] = lhist[i];
    __syncthreads();
    for (int off = 1; off < PSZ; off <<= 1) {
        int a0 = 0, a1 = 0;
        int i0 = t, i1 = t + 256;
        if (i0 < nd && i0 >= off) a0 = lexcl[i0 - off];
        if (i1 < nd && i1 >= off) a1 = lexcl[i1 - off];
        __syncthreads();
        if (i0 < nd) lexcl[i0] += a0;
        if (i1 < nd) lexcl[i1] += a1;
        __syncthreads();
    }
    for (int i = t; i < nd; i += 256) {
        lexcl[i] -= lhist[i];                        // exclusive
        rowptr[d0 + i] = base + lexcl[i];
    }
    __syncthreads();
    for (int i = t; i < n; i += 256) {
        unsigned r = recs[i];
        int li = (int)(r & 0xFFFFu) - d0;
        int pos = base + lexcl[li] + atomicAdd(&lcur[li], 1);
        colidx[pos] = (int)(r >> 16);
    }
}

// ---------------- generic GEMM (K=39 encoder-1 only) ----------------
template <int NC, bool RELU>
__global__ __launch_bounds__(256) void gemm_small_kernel(const float* __restrict__ A,
                                                         const float* __restrict__ B,
                                                         const float* __restrict__ bias,
                                                         float* __restrict__ C, int M, int K) {
    constexpr int TM = 32;
    constexpr int GROUPS = 256 / NC;
    constexpr int RPG = TM / GROUPS;
    constexpr int KC = 64;
    __shared__ float As[TM * 128];
    __shared__ float Bs[KC * NC];
    int t = threadIdx.x;
    int i0 = blockIdx.x * TM;

    int rows = M - i0; if (rows > TM) rows = TM;
    for (int idx = t; idx < rows * K; idx += 256) {
        int r = idx / K, k = idx - r * K;
        As[r * K + k] = A[(size_t)(i0 + r) * K + k];
    }

    int col = t % NC, grp = t / NC;
    int rg0 = grp * RPG;
    float acc[RPG];
#pragma unroll
    for (int r = 0; r < RPG; ++r) acc[r] = 0.f;

    for (int k0 = 0; k0 < K; k0 += KC) {
        int kc = K - k0; if (kc > KC) kc = KC;
        __syncthreads();
        for (int idx = t; idx < kc * NC; idx += 256) Bs[idx] = B[(size_t)k0 * NC + idx];
        __syncthreads();
        for (int k = 0; k < kc; ++k) {
            float bv = Bs[k * NC + col];
#pragma unroll
            for (int r = 0; r < RPG; ++r) acc[r] += As[(rg0 + r) * K + k0 + k] * bv;
        }
    }

    float bb = bias ? bias[col] : 0.f;
#pragma unroll
    for (int r = 0; r < RPG; ++r) {
        int i = i0 + rg0 + r;
        if (i < M) {
            float v = acc[r] + bb;
            if (RELU) v = v > 0.f ? v : 0.f;
            C[(size_t)i * NC + col] = v;
        }
    }
}

// ---------------- fast GEMM 128x128, thread owns cols tc*4..tc*4+3 (all-float4 LDS) ----------------
template <bool BIAS, bool EPI>
__global__ __launch_bounds__(256) void gemm128_kernel(const float* __restrict__ A,
                                                      const float* __restrict__ B,
                                                      const float* __restrict__ bias,
                                                      float* __restrict__ C,
                                                      const float* __restrict__ a_s,
                                                      const float* __restrict__ a_d,
                                                      float* __restrict__ es,
                                                      float* __restrict__ ed, int M) {
    __shared__ float As[64 * 128];
    __shared__ float Bs[64 * 128];
    int t = threadIdx.x;
    int i0 = blockIdx.x * 64;
    int tc = t & 31;                 // cols tc*4 .. tc*4+3
    int tr = t >> 5;
    int r0 = tr * 8;
    int c0 = tc * 4;

    for (int idx = t * 4; idx < 64 * 128; idx += 1024) {
        int r = idx >> 7, k = idx & 127;
        float4 v4 = make_float4(0.f, 0.f, 0.f, 0.f);
        if (i0 + r < M) v4 = *(const float4*)&A[(size_t)(i0 + r) * 128 + k];
        *(float4*)&As[idx] = v4;
    }

    float acc[8][4];
#pragma unroll
    for (int i = 0; i < 8; ++i)
#pragma unroll
        for (int j = 0; j < 4; ++j) acc[i][j] = 0.f;

    for (int k0 = 0; k0 < 128; k0 += 64) {
        __syncthreads();
        for (int idx = t * 4; idx < 64 * 128; idx += 1024)
            *(float4*)&Bs[idx] = *(const float4*)&B[(size_t)k0 * 128 + idx];
        __syncthreads();
#pragma unroll 4
        for (int k = 0; k < 64; k += 4) {
            float4 a4[8];
#pragma unroll
            for (int i = 0; i < 8; ++i)
                a4[i] = *(const float4*)&As[(r0 + i) * 128 + k0 + k];
            float4 b4[4];
#pragma unroll
            for (int kk = 0; kk < 4; ++kk)
                b4[kk] = *(const float4*)&Bs[(k + kk) * 128 + c0];
#pragma unroll
            for (int i = 0; i < 8; ++i) {
                const float* av = (const float*)&a4[i];
#pragma unroll
                for (int kk = 0; kk < 4; ++kk) {
                    acc[i][0] += av[kk] * b4[kk].x;
                    acc[i][1] += av[kk] * b4[kk].y;
                    acc[i][2] += av[kk] * b4[kk].z;
                    acc[i][3] += av[kk] * b4[kk].w;
                }
            }
        }
    }

    float4 bias4 = make_float4(0.f, 0.f, 0.f, 0.f);
    if (BIAS) bias4 = *(const float4*)&bias[c0];
#pragma unroll
    for (int i = 0; i < 8; ++i) {
        int row = i0 + r0 + i;
        if (row < M) {
            float4 o;
            o.x = acc[i][0] + bias4.x;
            o.y = acc[i][1] + bias4.y;
            o.z = acc[i][2] + bias4.z;
            o.w = acc[i][3] + bias4.w;
            *(float4*)&C[(size_t)row * 128 + c0] = o;
        }
    }

    if (EPI) {
        // head of this thread's 4 cols: hd = c0>>5 = tc>>3; reduce over the 8-lane octet
        int hd = tc >> 3;
        float4 s4 = *(const float4*)&a_s[c0];
        float4 d4 = *(const float4*)&a_d[c0];
#pragma unroll
        for (int i = 0; i < 8; ++i) {
            int row = i0 + r0 + i;
            float s = acc[i][0] * s4.x + acc[i][1] * s4.y + acc[i][2] * s4.z + acc[i][3] * s4.w;
            float d = acc[i][0] * d4.x + acc[i][1] * d4.y + acc[i][2] * d4.z + acc[i][3] * d4.w;
#pragma unroll
            for (int off = 4; off >= 1; off >>= 1) {
                s += __shfl_xor(s, off);
                d += __shfl_xor(d, off);
            }
            if ((tc & 7) == 0 && row < M) {
                es[row * 4 + hd] = s;
                ed[row * 4 + hd] = d;
            }
        }
    }
}

// ---------------- head GEMMs fully fused: h -> out (impact+timing) ----------------
__global__ __launch_bounds__(256) void gemm_heads_kernel(const float* __restrict__ A,
                                                         const float* __restrict__ iw1,
                                                         const float* __restrict__ ib1,
                                                         const float* __restrict__ tw1,
                                                         const float* __restrict__ tb1,
                                                         const float* __restrict__ iw2,
                                                         const float* __restrict__ ib2,
                                                         const float* __restrict__ tw2,
                                                         const float* __restrict__ tb2,
                                                         float* __restrict__ out, int M) {
    __shared__ float As[64 * 128];
    __shared__ float Bs[64 * 128];
    int t = threadIdx.x;
    int i0 = blockIdx.x * 64;
    int tc = t & 31;
    int tr = t >> 5;
    int r0 = tr * 8;
    int c0 = tc * 4;                 // virtual col (0-63 impact, 64-127 timing)

    for (int idx = t * 4; idx < 64 * 128; idx += 1024) {
        int r = idx >> 7, k = idx & 127;
        float4 v4 = make_float4(0.f, 0.f, 0.f, 0.f);
        if (i0 + r < M) v4 = *(const float4*)&A[(size_t)(i0 + r) * 128 + k];
        *(float4*)&As[idx] = v4;
    }

    float acc[8][4];
#pragma unroll
    for (int i = 0; i < 8; ++i)
#pragma unroll
        for (int j = 0; j < 4; ++j) acc[i][j] = 0.f;

    for (int k0 = 0; k0 < 128; k0 += 64) {
        __syncthreads();
        for (int idx = t * 4; idx < 64 * 128; idx += 1024) {
            int k = idx >> 7, cl = idx & 127;
            float4 v4 = (cl < 64)
                ? *(const float4*)&iw1[(size_t)(k0 + k) * 64 + cl]
                : *(const float4*)&tw1[(size_t)(k0 + k) * 64 + (cl - 64)];
            *(float4*)&Bs[idx] = v4;
        }
        __syncthreads();
#pragma unroll 4
        for (int k = 0; k < 64; k += 4) {
            float4 a4[8];
#pragma unroll
            for (int i = 0; i < 8; ++i)
                a4[i] = *(const float4*)&As[(r0 + i) * 128 + k0 + k];
            float4 b4[4];
#pragma unroll
            for (int kk = 0; kk < 4; ++kk)
                b4[kk] = *(const float4*)&Bs[(k + kk) * 128 + c0];
#pragma unroll
            for (int i = 0; i < 8; ++i) {
                const float* av = (const float*)&a4[i];
#pragma unroll
                for (int kk = 0; kk < 4; ++kk) {
                    acc[i][0] += av[kk] * b4[kk].x;
                    acc[i][1] += av[kk] * b4[kk].y;
                    acc[i][2] += av[kk] * b4[kk].z;
                    acc[i][3] += av[kk] * b4[kk].w;
                }
            }
        }
    }

    // epilogue: relu(acc + b1); thread's 4 cols entirely in impact (tc<16) or timing (tc>=16)
    bool isimp = (tc < 16);
    int lc = isimp ? c0 : (c0 - 64);   // local col in its head MLP
    float v[8][4];
#pragma unroll
    for (int i = 0; i < 8; ++i)
#pragma unroll
        for (int j = 0; j < 4; ++j) {
            float b = isimp ? ib1[lc + j] : tb1[lc + j];
            float x = acc[i][j] + b;
            v[i][j] = x > 0.f ? x : 0.f;
        }
#pragma unroll
    for (int i = 0; i < 8; ++i) {
        int row = i0 + r0 + i;
        if (isimp) {
#pragma unroll
            for (int c = 0; c < 3; ++c) {
                float pc = v[i][0] * iw2[(lc + 0) * 3 + c] + v[i][1] * iw2[(lc + 1) * 3 + c]
                         + v[i][2] * iw2[(lc + 2) * 3 + c] + v[i][3] * iw2[(lc + 3) * 3 + c];
#pragma unroll
                for (int off = 8; off >= 1; off >>= 1) pc += __shfl_xor(pc, off);
                if (tc == 0 && row < M) out[(size_t)row * 3 + c] = pc + ib2[c];
            }
        } else {
#pragma unroll
            for (int d = 0; d < 2; ++d) {
                float pd = v[i][0] * tw2[(lc + 0) * 2 + d] + v[i][1] * tw2[(lc + 1) * 2 + d]
                         + v[i][2] * tw2[(lc + 2) * 2 + d] + v[i][3] * tw2[(lc + 3) * 2 + d];
#pragma unroll
                for (int off = 8; off >= 1; off >>= 1) pd += __shfl_xor(pd, off);
                if (tc == 16 && row < M) {
                    float a = pd + tb2[d];
                    float sp = a > 20.f ? a : log1pf(__expf(a));
                    out[(size_t)(NN * 3) + (size_t)row * 2 + d] = sp;
                }
            }
        }
    }
}

// ---------------- gat v6: fused weights; wave per node; lane owns channels (2l,2l+1) ----------------
__global__ __launch_bounds__(256) void gat_kernel(const float* __restrict__ xp,
                                                  const float* __restrict__ es,
                                                  const float* __restrict__ ed,
                                                  const int* __restrict__ rowptr,
                                                  const int* __restrict__ colidx,
                                                  float* __restrict__ h,   // in-out (residual)
                                                  const float* __restrict__ bc,
                                                  const float* __restrict__ g,
                                                  const float* __restrict__ be) {
    int wv = threadIdx.x >> 6, l = threadIdx.x & 63;
    int v = blockIdx.x * 4 + wv;
    if (v >= NN) return;
    int s0 = rowptr[v], s1 = rowptr[v + 1];
    int hd = l >> 4;                       // head of channels 2l, 2l+1
    float edv = ed[v * 4 + hd];
    float ax = 0.f, ay = 0.f, den = 0.f;   // den identical across the 16 lanes of a head
    int p = s0;
    for (; p + 4 <= s1; p += 4) {
        int u0 = colidx[p], u1 = colidx[p + 1], u2 = colidx[p + 2], u3 = colidx[p + 3];
        float e0 = es[u0 * 4 + hd] + edv; e0 = e0 > 0.f ? e0 : 0.2f * e0;
        float e1 = es[u1 * 4 + hd] + edv; e1 = e1 > 0.f ? e1 : 0.2f * e1;
        float e2 = es[u2 * 4 + hd] + edv; e2 = e2 > 0.f ? e2 : 0.2f * e2;
        float e3 = es[u3 * 4 + hd] + edv; e3 = e3 > 0.f ? e3 : 0.2f * e3;
        float w0 = __expf(e0), w1 = __expf(e1), w2 = __expf(e2), w3 = __expf(e3);
        float2 x0 = *(const float2*)&xp[(size_t)u0 * 128 + 2 * l];
        float2 x1 = *(const float2*)&xp[(size_t)u1 * 128 + 2 * l];
        float2 x2 = *(const float2*)&xp[(size_t)u2 * 128 + 2 * l];
        float2 x3 = *(const float2*)&xp[(size_t)u3 * 128 + 2 * l];
        ax += w0 * x0.x; ay += w0 * x0.y;
        ax += w1 * x1.x; ay += w1 * x1.y;
        ax += w2 * x2.x; ay += w2 * x2.y;
        ax += w3 * x3.x; ay += w3 * x3.y;
        den += w0 + w1 + w2 + w3;
    }
    for (; p < s1; ++p) {
        int u = colidx[p];
        float e = es[u * 4 + hd] + edv; e = e > 0.f ? e : 0.2f * e;
        float w = __expf(e);               // no max-shift: |e| small, softmax shift-invariant
        float2 x = *(const float2*)&xp[(size_t)u * 128 + 2 * l];
        ax += w * x.x; ay += w * x.y;
        den += w;
    }
    float rd = 1.f / den;

    float2 h2  = *(const float2*)&h[(size_t)v * 128 + 2 * l];
    float2 bc2 = *(const float2*)&bc[2 * l];
    float y0 = ax * rd + bc2.x + h2.x;
    float y1 = ay * rd + bc2.y + h2.y;

    float s = y0 + y1;
#pragma unroll
    for (int off = 32; off >= 1; off >>= 1) s += __shfl_xor(s, off);
    float mean = s * (1.f / 128.f);
    float d0 = y0 - mean, d1 = y1 - mean;
    float vv = d0 * d0 + d1 * d1;
#pragma unroll
    for (int off = 32; off >= 1; off >>= 1) vv += __shfl_xor(vv, off);
    float rstd = rsqrtf(vv * (1.f / 128.f) + 1e-5f);
    float2 g2  = *(const float2*)&g[2 * l];
    float2 be2 = *(const float2*)&be[2 * l];
    float z0 = d0 * rstd * g2.x + be2.x;
    float z1 = d1 * rstd * g2.y + be2.y;
    float2 o;
    o.x = z0 > 0.f ? z0 : 0.f;
    o.y = z1 > 0.f ? z1 : 0.f;
    *(float2*)&h[(size_t)v * 128 + 2 * l] = o;
}

extern "C" void kernel_launch(void* const* d_in, const int* in_sizes, int n_in,
                              void* d_out, int out_size, void* d_ws, size_t ws_size,
                              hipStream_t stream) {
    const float* x      = (const float*)d_in[0];
    const int*   ei     = (const int*)d_in[1];
    const float* enc_w1 = (const float*)d_in[2];
    const float* enc_b1 = (const float*)d_in[3];
    const float* enc_w2 = (const float*)d_in[4];
    const float* enc_b2 = (const float*)d_in[5];
    const float *W[3], *as_[3], *ad_[3], *bc[3], *g[3], *be[3];
    for (int l = 0; l < 3; ++l) {
        W[l]   = (const float*)d_in[6 + l * 6 + 0];
        as_[l] = (const float*)d_in[6 + l * 6 + 1];
        ad_[l] = (const float*)d_in[6 + l * 6 + 2];
        bc[l]  = (const float*)d_in[6 + l * 6 + 3];
        g[l]   = (const float*)d_in[6 + l * 6 + 4];
        be[l]  = (const float*)d_in[6 + l * 6 + 5];
    }
    const float* imp_w1 = (const float*)d_in[24];
    const float* imp_b1 = (const float*)d_in[25];
    const float* imp_w2 = (const float*)d_in[26];
    const float* imp_b2 = (const float*)d_in[27];
    const float* tim_w1 = (const float*)d_in[28];
    const float* tim_b1 = (const float*)d_in[29];
    const float* tim_w2 = (const float*)d_in[30];
    const float* tim_b2 = (const float*)d_in[31];

    int* flag    = (int*)d_ws;               // 64 ints
    int* gcursor = flag + 64;                // NPART
    int* pbase   = gcursor + NPART;          // NPART + pad
    int* rowptr  = pbase + NPART + 64;       // NN+1
    int* colidx  = rowptr + NN + 1;          // ETOT
    uintptr_t pb = (uintptr_t)(colidx + ETOT);
    pb = (pb + 255) & ~(uintptr_t)255;
    unsigned* pbuf = (unsigned*)pb;          // NPART*PCAP (7.2 MB)
    uintptr_t fb = (uintptr_t)(pbuf + (size_t)NPART * PCAP);
    fb = (fb + 255) & ~(uintptr_t)255;
    float* es = (float*)fb;                  // NN*4
    float* ed = es + (size_t)NN * 4;         // NN*4
    float* h  = ed + (size_t)NN * 4;         // NN*128
    float* xp = h + (size_t)NN * 128;        // NN*128
    float* tmp = xp;                         // enc1 scratch aliases xp

    hipMemsetAsync(d_ws, 0, (64 + NPART) * sizeof(int), stream);
    detect_kernel<<<16, 256, 0, stream>>>(ei, flag);
    pass1_kernel<<<512, 256, 0, stream>>>(ei, flag, gcursor, pbuf);
    scan_part_kernel<<<1, NPART, 0, stream>>>(gcursor, pbase, rowptr + NN);
    pass2_kernel<<<NPART, 256, 0, stream>>>(pbuf, gcursor, pbase, rowptr, colidx);

    const int GB64 = (NN + 63) / 64;
    gemm_small_kernel<128, true><<<(NN + 31) / 32, 256, 0, stream>>>(x, enc_w1, enc_b1, tmp, NN, FINDIM);
    gemm128_kernel<true, false><<<GB64, 256, 0, stream>>>(tmp, enc_w2, enc_b2, h,
                                                          nullptr, nullptr, nullptr, nullptr, NN);

    for (int l = 0; l < 3; ++l) {
        gemm128_kernel<false, true><<<GB64, 256, 0, stream>>>(h, W[l], nullptr, xp,
                                                              as_[l], ad_[l], es, ed, NN);
        gat_kernel<<<(NN + 3) / 4, 256, 0, stream>>>(xp, es, ed, rowptr, colidx, h,
                                                     bc[l], g[l], be[l]);
    }

    gemm_heads_kernel<<<GB64, 256, 0, stream>>>(h, imp_w1, imp_b1, tim_w1, tim_b1,
                                                imp_w2, imp_b2, tim_w2, tim_b2,
                                                (float*)d_out, NN);
}

// Round 11
// 741.977 us; speedup vs baseline: 2.2775x; 1.1199x over previous
//
#include <hip/hip_runtime.h>
#include <hip/hip_bf16.h>
#include <math.h>

#define NN 50000
#define EDGES 1600000
#define ETOT (EDGES + NN)
#define FINDIM 39
#define NPART 128
#define PSZ 391        // dsts per partition; 128*391 = 50048 >= NN
#define PCAP 14000     // capacity per partition (avg 12891, +9.8 sigma)
#define P1TILE 4096

// ---------------- edge_index dtype sniffer (int64 safety net) ----------------
__global__ void detect_kernel(const int* __restrict__ ei, int* __restrict__ flag) {
    int t = blockIdx.x * blockDim.x + threadIdx.x;   // 4096 threads
    if (ei[2 * t + 1] != 0) atomicOr(flag, 1);       // flag=1 -> int32
}

__device__ __forceinline__ int src_at(const int* ei, int i, bool i32) {
    return i32 ? ei[i] : ei[2 * i];
}
__device__ __forceinline__ int dst_at(const int* ei, int i, bool i32) {
    return i32 ? ei[EDGES + i] : ei[2 * (EDGES + i)];
}

// ---------------- CSR pass 1: bucket edges into 128 dst-range partitions ----------------
__global__ __launch_bounds__(256) void pass1_kernel(const int* __restrict__ ei,
                                                    const int* __restrict__ flag,
                                                    int* __restrict__ gcursor,
                                                    unsigned* __restrict__ pbuf) {
    __shared__ unsigned raw[P1TILE];
    __shared__ unsigned srt[P1TILE];
    __shared__ int pcnt[NPART], poff[NPART], pcur[NPART], gb[NPART];
    bool i32 = (*flag != 0);
    int chunk = (ETOT + gridDim.x - 1) / gridDim.x;
    int c0 = blockIdx.x * chunk;
    int c1 = c0 + chunk; if (c1 > ETOT) c1 = ETOT;
    int t = threadIdx.x;
    for (int t0 = c0; t0 < c1; t0 += P1TILE) {
        int tn = c1 - t0; if (tn > P1TILE) tn = P1TILE;
        if (t < NPART) { pcnt[t] = 0; pcur[t] = 0; }
        __syncthreads();
        for (int i = t; i < tn; i += 256) {
            int e = t0 + i;
            int s, d;
            if (e < EDGES) { s = src_at(ei, e, i32); d = dst_at(ei, e, i32); }
            else { s = d = e - EDGES; }
            raw[i] = ((unsigned)s << 16) | (unsigned)d;
            atomicAdd(&pcnt[d / PSZ], 1);
        }
        __syncthreads();
        if (t < NPART) poff[t] = pcnt[t];
        __syncthreads();
        for (int off = 1; off < NPART; off <<= 1) {
            int v = 0;
            if (t < NPART && t >= off) v = poff[t - off];
            __syncthreads();
            if (t < NPART) poff[t] += v;
            __syncthreads();
        }
        if (t < NPART) {
            poff[t] -= pcnt[t];                       // exclusive
            gb[t] = atomicAdd(&gcursor[t], pcnt[t]);  // global base for this tile's run
        }
        __syncthreads();
        for (int i = t; i < tn; i += 256) {
            unsigned r = raw[i];
            int part = (int)(r & 0xFFFFu) / PSZ;
            int pos = poff[part] + atomicAdd(&pcur[part], 1);
            srt[pos] = r;
        }
        __syncthreads();
        for (int i = t; i < tn; i += 256) {
            unsigned r = srt[i];
            int part = (int)(r & 0xFFFFu) / PSZ;
            int gpos = gb[part] + (i - poff[part]);
            if (gpos < PCAP) pbuf[(size_t)part * PCAP + gpos] = r;
        }
        __syncthreads();
    }
}

// ---------------- CSR: scan 128 partition totals ----------------
__global__ __launch_bounds__(128) void scan_part_kernel(const int* __restrict__ gcursor,
                                                        int* __restrict__ pbase,
                                                        int* __restrict__ rowptrN) {
    __shared__ int sm[NPART];
    int t = threadIdx.x;
    int v = gcursor[t];
    sm[t] = v;
    __syncthreads();
    for (int off = 1; off < NPART; off <<= 1) {
        int x = (t >= off) ? sm[t - off] : 0;
        __syncthreads();
        sm[t] += x;
        __syncthreads();
    }
    pbase[t] = sm[t] - v;
    if (t == NPART - 1) *rowptrN = sm[t];   // == ETOT
}

// ---------------- CSR pass 2: per-partition exact sort -> rowptr + colidx ----------------
__global__ __launch_bounds__(256) void pass2_kernel(const unsigned* __restrict__ pbuf,
                                                    const int* __restrict__ gcursor,
                                                    const int* __restrict__ pbase,
                                                    int* __restrict__ rowptr,
                                                    int* __restrict__ colidx) {
    __shared__ unsigned recs[PCAP];                 // 56 KB
    __shared__ int lhist[PSZ], lexcl[PSZ], lcur[PSZ];
    int p = blockIdx.x;
    int t = threadIdx.x;
    int n = gcursor[p]; if (n > PCAP) n = PCAP;
    int base = pbase[p];
    int d0 = p * PSZ;
    int nd = NN - d0; if (nd > PSZ) nd = PSZ;
    for (int i = t; i < nd; i += 256) { lhist[i] = 0; lcur[i] = 0; }
    __syncthreads();
    for (int i = t; i < n; i += 256) {
        unsigned r = pbuf[(size_t)p * PCAP + i];
        recs[i] = r;
        atomicAdd(&lhist[(int)(r & 0xFFFFu) - d0], 1);
    }
    __syncthreads();
    for (int i = t; i < nd; i += 256) lexcl[i] = lhist[i];
    __syncthreads();
    for (int off = 1; off < PSZ; off <<= 1) {
        int a0 = 0, a1 = 0;
        int i0 = t, i1 = t + 256;
        if (i0 < nd && i0 >= off) a0 = lexcl[i0 - off];
        if (i1 < nd && i1 >= off) a1 = lexcl[i1 - off];
        __syncthreads();
        if (i0 < nd) lexcl[i0] += a0;
        if (i1 < nd) lexcl[i1] += a1;
        __syncthreads();
    }
    for (int i = t; i < nd; i += 256) {
        lexcl[i] -= lhist[i];                        // exclusive
        rowptr[d0 + i] = base + lexcl[i];
    }
    __syncthreads();
    for (int i = t; i < n; i += 256) {
        unsigned r = recs[i];
        int li = (int)(r & 0xFFFFu) - d0;
        int pos = base + lexcl[li] + atomicAdd(&lcur[li], 1);
        colidx[pos] = (int)(r >> 16);
    }
}

// ---------------- generic GEMM (K=39 encoder-1 only) ----------------
template <int NC, bool RELU>
__global__ __launch_bounds__(256) void gemm_small_kernel(const float* __restrict__ A,
                                                         const float* __restrict__ B,
                                                         const float* __restrict__ bias,
                                                         float* __restrict__ C, int M, int K) {
    constexpr int TM = 32;
    constexpr int GROUPS = 256 / NC;
    constexpr int RPG = TM / GROUPS;
    constexpr int KC = 64;
    __shared__ float As[TM * 128];
    __shared__ float Bs[KC * NC];
    int t = threadIdx.x;
    int i0 = blockIdx.x * TM;

    int rows = M - i0; if (rows > TM) rows = TM;
    for (int idx = t; idx < rows * K; idx += 256) {
        int r = idx / K, k = idx - r * K;
        As[r * K + k] = A[(size_t)(i0 + r) * K + k];
    }

    int col = t % NC, grp = t / NC;
    int rg0 = grp * RPG;
    float acc[RPG];
#pragma unroll
    for (int r = 0; r < RPG; ++r) acc[r] = 0.f;

    for (int k0 = 0; k0 < K; k0 += KC) {
        int kc = K - k0; if (kc > KC) kc = KC;
        __syncthreads();
        for (int idx = t; idx < kc * NC; idx += 256) Bs[idx] = B[(size_t)k0 * NC + idx];
        __syncthreads();
        for (int k = 0; k < kc; ++k) {
            float bv = Bs[k * NC + col];
#pragma unroll
            for (int r = 0; r < RPG; ++r) acc[r] += As[(rg0 + r) * K + k0 + k] * bv;
        }
    }

    float bb = bias ? bias[col] : 0.f;
#pragma unroll
    for (int r = 0; r < RPG; ++r) {
        int i = i0 + rg0 + r;
        if (i < M) {
            float v = acc[r] + bb;
            if (RELU) v = v > 0.f ? v : 0.f;
            C[(size_t)i * NC + col] = v;
        }
    }
}

// ---------------- fast GEMM 128x128, 24KB LDS (k-chunked), cols tc*4..tc*4+3 ----------------
template <bool BIAS, bool EPI>
__global__ __launch_bounds__(256) void gemm128_kernel(const float* __restrict__ A,
                                                      const float* __restrict__ B,
                                                      const float* __restrict__ bias,
                                                      float* __restrict__ C,
                                                      const float* __restrict__ a_s,
                                                      const float* __restrict__ a_d,
                                                      float* __restrict__ es,
                                                      float* __restrict__ ed, int M) {
    __shared__ float As[64 * 32];    // 8 KB : 64 rows x 32-k chunk
    __shared__ float Bs[32 * 128];   // 16 KB: 32-k chunk x 128 cols
    int t = threadIdx.x;
    int i0 = blockIdx.x * 64;
    int tc = t & 31;                 // cols tc*4 .. tc*4+3
    int tr = t >> 5;
    int r0 = tr * 8;
    int c0 = tc * 4;

    float acc[8][4];
#pragma unroll
    for (int i = 0; i < 8; ++i)
#pragma unroll
        for (int j = 0; j < 4; ++j) acc[i][j] = 0.f;

    for (int k0 = 0; k0 < 128; k0 += 32) {
        __syncthreads();             // prev chunk consumed
        // As chunk: 64 rows x 32 k = 512 float4 (2/thread)
#pragma unroll
        for (int q = 0; q < 2; ++q) {
            int idx = t + q * 256;           // 0..511
            int r = idx >> 3, kq = idx & 7;  // row, k-quad
            float4 v4 = make_float4(0.f, 0.f, 0.f, 0.f);
            if (i0 + r < M) v4 = *(const float4*)&A[(size_t)(i0 + r) * 128 + k0 + kq * 4];
            *(float4*)&As[r * 32 + kq * 4] = v4;
        }
        // Bs chunk: 32 k x 128 cols = 1024 float4 (4/thread), contiguous
#pragma unroll
        for (int q = 0; q < 4; ++q) {
            int idx = (t + q * 256) * 4;
            *(float4*)&Bs[idx] = *(const float4*)&B[(size_t)k0 * 128 + idx];
        }
        __syncthreads();
#pragma unroll 8
        for (int k = 0; k < 32; k += 4) {
            float4 a4[8];
#pragma unroll
            for (int i = 0; i < 8; ++i)
                a4[i] = *(const float4*)&As[(r0 + i) * 32 + k];
            float4 b4[4];
#pragma unroll
            for (int kk = 0; kk < 4; ++kk)
                b4[kk] = *(const float4*)&Bs[(k + kk) * 128 + c0];
#pragma unroll
            for (int i = 0; i < 8; ++i) {
                const float* av = (const float*)&a4[i];
#pragma unroll
                for (int kk = 0; kk < 4; ++kk) {
                    acc[i][0] += av[kk] * b4[kk].x;
                    acc[i][1] += av[kk] * b4[kk].y;
                    acc[i][2] += av[kk] * b4[kk].z;
                    acc[i][3] += av[kk] * b4[kk].w;
                }
            }
        }
    }

    float4 bias4 = make_float4(0.f, 0.f, 0.f, 0.f);
    if (BIAS) bias4 = *(const float4*)&bias[c0];
#pragma unroll
    for (int i = 0; i < 8; ++i) {
        int row = i0 + r0 + i;
        if (row < M) {
            float4 o;
            o.x = acc[i][0] + bias4.x;
            o.y = acc[i][1] + bias4.y;
            o.z = acc[i][2] + bias4.z;
            o.w = acc[i][3] + bias4.w;
            *(float4*)&C[(size_t)row * 128 + c0] = o;
        }
    }

    if (EPI) {
        // head of this thread's 4 cols: hd = tc>>3; reduce over the 8-lane octet
        int hd = tc >> 3;
        float4 s4 = *(const float4*)&a_s[c0];
        float4 d4 = *(const float4*)&a_d[c0];
#pragma unroll
        for (int i = 0; i < 8; ++i) {
            int row = i0 + r0 + i;
            float s = acc[i][0] * s4.x + acc[i][1] * s4.y + acc[i][2] * s4.z + acc[i][3] * s4.w;
            float d = acc[i][0] * d4.x + acc[i][1] * d4.y + acc[i][2] * d4.z + acc[i][3] * d4.w;
#pragma unroll
            for (int off = 4; off >= 1; off >>= 1) {
                s += __shfl_xor(s, off);
                d += __shfl_xor(d, off);
            }
            if ((tc & 7) == 0 && row < M) {
                es[row * 4 + hd] = s;
                ed[row * 4 + hd] = d;
            }
        }
    }
}

// ---------------- head GEMMs fully fused: h -> out (impact+timing), 24KB LDS ----------------
__global__ __launch_bounds__(256) void gemm_heads_kernel(const float* __restrict__ A,
                                                         const float* __restrict__ iw1,
                                                         const float* __restrict__ ib1,
                                                         const float* __restrict__ tw1,
                                                         const float* __restrict__ tb1,
                                                         const float* __restrict__ iw2,
                                                         const float* __restrict__ ib2,
                                                         const float* __restrict__ tw2,
                                                         const float* __restrict__ tb2,
                                                         float* __restrict__ out, int M) {
    __shared__ float As[64 * 32];
    __shared__ float Bs[32 * 128];
    int t = threadIdx.x;
    int i0 = blockIdx.x * 64;
    int tc = t & 31;
    int tr = t >> 5;
    int r0 = tr * 8;
    int c0 = tc * 4;                 // virtual col (0-63 impact, 64-127 timing)

    float acc[8][4];
#pragma unroll
    for (int i = 0; i < 8; ++i)
#pragma unroll
        for (int j = 0; j < 4; ++j) acc[i][j] = 0.f;

    for (int k0 = 0; k0 < 128; k0 += 32) {
        __syncthreads();
#pragma unroll
        for (int q = 0; q < 2; ++q) {
            int idx = t + q * 256;
            int r = idx >> 3, kq = idx & 7;
            float4 v4 = make_float4(0.f, 0.f, 0.f, 0.f);
            if (i0 + r < M) v4 = *(const float4*)&A[(size_t)(i0 + r) * 128 + k0 + kq * 4];
            *(float4*)&As[r * 32 + kq * 4] = v4;
        }
#pragma unroll
        for (int q = 0; q < 4; ++q) {
            int idx = (t + q * 256) * 4;       // flat into [32][128]
            int k = idx >> 7, cl = idx & 127;
            float4 v4 = (cl < 64)
                ? *(const float4*)&iw1[(size_t)(k0 + k) * 64 + cl]
                : *(const float4*)&tw1[(size_t)(k0 + k) * 64 + (cl - 64)];
            *(float4*)&Bs[idx] = v4;
        }
        __syncthreads();
#pragma unroll 8
        for (int k = 0; k < 32; k += 4) {
            float4 a4[8];
#pragma unroll
            for (int i = 0; i < 8; ++i)
                a4[i] = *(const float4*)&As[(r0 + i) * 32 + k];
            float4 b4[4];
#pragma unroll
            for (int kk = 0; kk < 4; ++kk)
                b4[kk] = *(const float4*)&Bs[(k + kk) * 128 + c0];
#pragma unroll
            for (int i = 0; i < 8; ++i) {
                const float* av = (const float*)&a4[i];
#pragma unroll
                for (int kk = 0; kk < 4; ++kk) {
                    acc[i][0] += av[kk] * b4[kk].x;
                    acc[i][1] += av[kk] * b4[kk].y;
                    acc[i][2] += av[kk] * b4[kk].z;
                    acc[i][3] += av[kk] * b4[kk].w;
                }
            }
        }
    }

    // epilogue: relu(acc + b1); thread's 4 cols entirely in impact (tc<16) or timing (tc>=16)
    bool isimp = (tc < 16);
    int lc = isimp ? c0 : (c0 - 64);
    float v[8][4];
#pragma unroll
    for (int i = 0; i < 8; ++i)
#pragma unroll
        for (int j = 0; j < 4; ++j) {
            float b = isimp ? ib1[lc + j] : tb1[lc + j];
            float x = acc[i][j] + b;
            v[i][j] = x > 0.f ? x : 0.f;
        }
#pragma unroll
    for (int i = 0; i < 8; ++i) {
        int row = i0 + r0 + i;
        if (isimp) {
#pragma unroll
            for (int c = 0; c < 3; ++c) {
                float pc = v[i][0] * iw2[(lc + 0) * 3 + c] + v[i][1] * iw2[(lc + 1) * 3 + c]
                         + v[i][2] * iw2[(lc + 2) * 3 + c] + v[i][3] * iw2[(lc + 3) * 3 + c];
#pragma unroll
                for (int off = 8; off >= 1; off >>= 1) pc += __shfl_xor(pc, off);
                if (tc == 0 && row < M) out[(size_t)row * 3 + c] = pc + ib2[c];
            }
        } else {
#pragma unroll
            for (int d = 0; d < 2; ++d) {
                float pd = v[i][0] * tw2[(lc + 0) * 2 + d] + v[i][1] * tw2[(lc + 1) * 2 + d]
                         + v[i][2] * tw2[(lc + 2) * 2 + d] + v[i][3] * tw2[(lc + 3) * 2 + d];
#pragma unroll
                for (int off = 8; off >= 1; off >>= 1) pd += __shfl_xor(pd, off);
                if (tc == 16 && row < M) {
                    float a = pd + tb2[d];
                    float sp = a > 20.f ? a : log1pf(__expf(a));
                    out[(size_t)(NN * 3) + (size_t)row * 2 + d] = sp;
                }
            }
        }
    }
}

// ---------------- gat: fused weights; wave per node; lane owns channels (2l,2l+1) ----------------
__global__ __launch_bounds__(256) void gat_kernel(const float* __restrict__ xp,
                                                  const float* __restrict__ es,
                                                  const float* __restrict__ ed,
                                                  const int* __restrict__ rowptr,
                                                  const int* __restrict__ colidx,
                                                  float* __restrict__ h,   // in-out (residual)
                                                  const float* __restrict__ bc,
                                                  const float* __restrict__ g,
                                                  const float* __restrict__ be) {
    int wv = threadIdx.x >> 6, l = threadIdx.x & 63;
    int v = blockIdx.x * 4 + wv;
    if (v >= NN) return;
    int s0 = rowptr[v], s1 = rowptr[v + 1];
    int hd = l >> 4;                       // head of channels 2l, 2l+1
    float edv = ed[v * 4 + hd];
    float ax = 0.f, ay = 0.f, den = 0.f;   // den identical across the 16 lanes of a head
    int p = s0;
    for (; p + 8 <= s1; p += 8) {          // deep unroll: 8 gathers in flight
        int u[8];
#pragma unroll
        for (int q = 0; q < 8; ++q) u[q] = colidx[p + q];
        float2 xv[8];
#pragma unroll
        for (int q = 0; q < 8; ++q) xv[q] = *(const float2*)&xp[(size_t)u[q] * 128 + 2 * l];
        float w[8];
#pragma unroll
        for (int q = 0; q < 8; ++q) {
            float e = es[u[q] * 4 + hd] + edv;
            e = e > 0.f ? e : 0.2f * e;
            w[q] = __expf(e);              // no max-shift: |e| small, softmax shift-invariant
        }
#pragma unroll
        for (int q = 0; q < 8; ++q) {
            ax += w[q] * xv[q].x; ay += w[q] * xv[q].y; den += w[q];
        }
    }
    for (; p < s1; ++p) {
        int u = colidx[p];
        float e = es[u * 4 + hd] + edv; e = e > 0.f ? e : 0.2f * e;
        float w = __expf(e);
        float2 x = *(const float2*)&xp[(size_t)u * 128 + 2 * l];
        ax += w * x.x; ay += w * x.y;
        den += w;
    }
    float rd = 1.f / den;

    float2 h2  = *(const float2*)&h[(size_t)v * 128 + 2 * l];
    float2 bc2 = *(const float2*)&bc[2 * l];
    float y0 = ax * rd + bc2.x + h2.x;
    float y1 = ay * rd + bc2.y + h2.y;

    float s = y0 + y1;
#pragma unroll
    for (int off = 32; off >= 1; off >>= 1) s += __shfl_xor(s, off);
    float mean = s * (1.f / 128.f);
    float d0 = y0 - mean, d1 = y1 - mean;
    float vv = d0 * d0 + d1 * d1;
#pragma unroll
    for (int off = 32; off >= 1; off >>= 1) vv += __shfl_xor(vv, off);
    float rstd = rsqrtf(vv * (1.f / 128.f) + 1e-5f);
    float2 g2  = *(const float2*)&g[2 * l];
    float2 be2 = *(const float2*)&be[2 * l];
    float z0 = d0 * rstd * g2.x + be2.x;
    float z1 = d1 * rstd * g2.y + be2.y;
    float2 o;
    o.x = z0 > 0.f ? z0 : 0.f;
    o.y = z1 > 0.f ? z1 : 0.f;
    *(float2*)&h[(size_t)v * 128 + 2 * l] = o;
}

extern "C" void kernel_launch(void* const* d_in, const int* in_sizes, int n_in,
                              void* d_out, int out_size, void* d_ws, size_t ws_size,
                              hipStream_t stream) {
    const float* x      = (const float*)d_in[0];
    const int*   ei     = (const int*)d_in[1];
    const float* enc_w1 = (const float*)d_in[2];
    const float* enc_b1 = (const float*)d_in[3];
    const float* enc_w2 = (const float*)d_in[4];
    const float* enc_b2 = (const float*)d_in[5];
    const float *W[3], *as_[3], *ad_[3], *bc[3], *g[3], *be[3];
    for (int l = 0; l < 3; ++l) {
        W[l]   = (const float*)d_in[6 + l * 6 + 0];
        as_[l] = (const float*)d_in[6 + l * 6 + 1];
        ad_[l] = (const float*)d_in[6 + l * 6 + 2];
        bc[l]  = (const float*)d_in[6 + l * 6 + 3];
        g[l]   = (const float*)d_in[6 + l * 6 + 4];
        be[l]  = (const float*)d_in[6 + l * 6 + 5];
    }
    const float* imp_w1 = (const float*)d_in[24];
    const float* imp_b1 = (const float*)d_in[25];
    const float* imp_w2 = (const float*)d_in[26];
    const float* imp_b2 = (const float*)d_in[27];
    const float* tim_w1 = (const float*)d_in[28];
    const float* tim_b1 = (const float*)d_in[29];
    const float* tim_w2 = (const float*)d_in[30];
    const float* tim_b2 = (const float*)d_in[31];

    int* flag    = (int*)d_ws;               // 64 ints
    int* gcursor = flag + 64;                // NPART
    int* pbase   = gcursor + NPART;          // NPART + pad
    int* rowptr  = pbase + NPART + 64;       // NN+1
    int* colidx  = rowptr + NN + 1;          // ETOT
    uintptr_t pb = (uintptr_t)(colidx + ETOT);
    pb = (pb + 255) & ~(uintptr_t)255;
    unsigned* pbuf = (unsigned*)pb;          // NPART*PCAP (7.2 MB)
    uintptr_t fb = (uintptr_t)(pbuf + (size_t)NPART * PCAP);
    fb = (fb + 255) & ~(uintptr_t)255;
    float* es = (float*)fb;                  // NN*4
    float* ed = es + (size_t)NN * 4;         // NN*4
    float* h  = ed + (size_t)NN * 4;         // NN*128
    float* xp = h + (size_t)NN * 128;        // NN*128
    float* tmp = xp;                         // enc1 scratch aliases xp

    hipMemsetAsync(d_ws, 0, (64 + NPART) * sizeof(int), stream);
    detect_kernel<<<16, 256, 0, stream>>>(ei, flag);
    pass1_kernel<<<512, 256, 0, stream>>>(ei, flag, gcursor, pbuf);
    scan_part_kernel<<<1, NPART, 0, stream>>>(gcursor, pbase, rowptr + NN);
    pass2_kernel<<<NPART, 256, 0, stream>>>(pbuf, gcursor, pbase, rowptr, colidx);

    const int GB64 = (NN + 63) / 64;
    gemm_small_kernel<128, true><<<(NN + 31) / 32, 256, 0, stream>>>(x, enc_w1, enc_b1, tmp, NN, FINDIM);
    gemm128_kernel<true, false><<<GB64, 256, 0, stream>>>(tmp, enc_w2, enc_b2, h,
                                                          nullptr, nullptr, nullptr, nullptr, NN);

    for (int l = 0; l < 3; ++l) {
        gemm128_kernel<false, true><<<GB64, 256, 0, stream>>>(h, W[l], nullptr, xp,
                                                              as_[l], ad_[l], es, ed, NN);
        gat_kernel<<<(NN + 3) / 4, 256, 0, stream>>>(xp, es, ed, rowptr, colidx, h,
                                                     bc[l], g[l], be[l]);
    }

    gemm_heads_kernel<<<GB64, 256, 0, stream>>>(h, imp_w1, imp_b1, tim_w1, tim_b1,
                                                imp_w2, imp_b2, tim_w2, tim_b2,
                                                (float*)d_out, NN);
}

// Round 12
// 589.729 us; speedup vs baseline: 2.8655x; 1.2582x over previous
//
#include <hip/hip_runtime.h>
#include <hip/hip_bf16.h>
#include <math.h>

#define NN 50000
#define EDGES 1600000
#define ETOT (EDGES + NN)
#define FINDIM 39
#define NPART 128
#define PSZ 391        // dsts per partition; 128*391 = 50048 >= NN
#define PCAP 14000     // capacity per partition (avg 12891, +9.8 sigma)
#define P1TILE 4096

__device__ __forceinline__ unsigned pack_bf16(float a, float b) {
    __hip_bfloat162 t;
    t.x = __float2bfloat16(a);
    t.y = __float2bfloat16(b);
    return *(unsigned*)&t;
}
__device__ __forceinline__ float2 unpack_bf16(unsigned w) {
    float2 r;
    r.x = __uint_as_float(w << 16);
    r.y = __uint_as_float(w & 0xffff0000u);
    return r;
}

__device__ __forceinline__ int src_at(const int* ei, int i, bool i32) {
    return i32 ? ei[i] : ei[2 * i];
}
__device__ __forceinline__ int dst_at(const int* ei, int i, bool i32) {
    return i32 ? ei[EDGES + i] : ei[2 * (EDGES + i)];
}

// ---------------- CSR pass 1 (self-detecting int32/int64): bucket into 128 partitions ----------------
__global__ __launch_bounds__(256) void pass1_kernel(const int* __restrict__ ei,
                                                    int* __restrict__ gcursor,
                                                    unsigned* __restrict__ pbuf) {
    __shared__ unsigned raw[P1TILE];
    __shared__ unsigned srt[P1TILE];
    __shared__ int pcnt[NPART], poff[NPART], pcur[NPART], gb[NPART];
    __shared__ int i32flag;
    int t = threadIdx.x;
    // per-block dtype detection: 64 odd-word samples; int64 => all zero
    if (t == 0) i32flag = 0;
    __syncthreads();
    int chunk = (ETOT + gridDim.x - 1) / gridDim.x;
    int c0 = blockIdx.x * chunk;
    int c1 = c0 + chunk; if (c1 > ETOT) c1 = ETOT;
    int sb = c0 < EDGES - 64 ? c0 : 0;
    if (t < 64 && ei[2 * (sb + t) + 1] != 0) i32flag = 1;
    __syncthreads();
    bool i32 = (i32flag != 0);
    for (int t0 = c0; t0 < c1; t0 += P1TILE) {
        int tn = c1 - t0; if (tn > P1TILE) tn = P1TILE;
        if (t < NPART) { pcnt[t] = 0; pcur[t] = 0; }
        __syncthreads();
        for (int i = t; i < tn; i += 256) {
            int e = t0 + i;
            int s, d;
            if (e < EDGES) { s = src_at(ei, e, i32); d = dst_at(ei, e, i32); }
            else { s = d = e - EDGES; }
            raw[i] = ((unsigned)s << 16) | (unsigned)d;
            atomicAdd(&pcnt[d / PSZ], 1);
        }
        __syncthreads();
        if (t < NPART) poff[t] = pcnt[t];
        __syncthreads();
        for (int off = 1; off < NPART; off <<= 1) {
            int v = 0;
            if (t < NPART && t >= off) v = poff[t - off];
            __syncthreads();
            if (t < NPART) poff[t] += v;
            __syncthreads();
        }
        if (t < NPART) {
            poff[t] -= pcnt[t];                       // exclusive
            gb[t] = atomicAdd(&gcursor[t], pcnt[t]);  // global base for this tile's run
        }
        __syncthreads();
        for (int i = t; i < tn; i += 256) {
            unsigned r = raw[i];
            int part = (int)(r & 0xFFFFu) / PSZ;
            int pos = poff[part] + atomicAdd(&pcur[part], 1);
            srt[pos] = r;
        }
        __syncthreads();
        for (int i = t; i < tn; i += 256) {
            unsigned r = srt[i];
            int part = (int)(r & 0xFFFFu) / PSZ;
            int gpos = gb[part] + (i - poff[part]);
            if (gpos < PCAP) pbuf[(size_t)part * PCAP + gpos] = r;
        }
        __syncthreads();
    }
}

// ---------------- CSR: scan 128 partition totals ----------------
__global__ __launch_bounds__(128) void scan_part_kernel(const int* __restrict__ gcursor,
                                                        int* __restrict__ pbase,
                                                        int* __restrict__ rowptrN) {
    __shared__ int sm[NPART];
    int t = threadIdx.x;
    int v = gcursor[t];
    sm[t] = v;
    __syncthreads();
    for (int off = 1; off < NPART; off <<= 1) {
        int x = (t >= off) ? sm[t - off] : 0;
        __syncthreads();
        sm[t] += x;
        __syncthreads();
    }
    pbase[t] = sm[t] - v;
    if (t == NPART - 1) *rowptrN = sm[t];   // == ETOT
}

// ---------------- CSR pass 2: per-partition exact sort -> rowptr + colidx ----------------
__global__ __launch_bounds__(256) void pass2_kernel(const unsigned* __restrict__ pbuf,
                                                    const int* __restrict__ gcursor,
                                                    const int* __restrict__ pbase,
                                                    int* __restrict__ rowptr,
                                                    int* __restrict__ colidx) {
    __shared__ unsigned recs[PCAP];                 // 56 KB
    __shared__ int lhist[PSZ], lexcl[PSZ], lcur[PSZ];
    int p = blockIdx.x;
    int t = threadIdx.x;
    int n = gcursor[p]; if (n > PCAP) n = PCAP;
    int base = pbase[p];
    int d0 = p * PSZ;
    int nd = NN - d0; if (nd > PSZ) nd = PSZ;
    for (int i = t; i < nd; i += 256) { lhist[i] = 0; lcur[i] = 0; }
    __syncthreads();
    for (int i = t; i < n; i += 256) {
        unsigned r = pbuf[(size_t)p * PCAP + i];
        recs[i] = r;
        atomicAdd(&lhist[(int)(r & 0xFFFFu) - d0], 1);
    }
    __syncthreads();
    for (int i = t; i < nd; i += 256) lexcl[i] = lhist[i];
    __syncthreads();
    for (int off = 1; off < PSZ; off <<= 1) {
        int a0 = 0, a1 = 0;
        int i0 = t, i1 = t + 256;
        if (i0 < nd && i0 >= off) a0 = lexcl[i0 - off];
        if (i1 < nd && i1 >= off) a1 = lexcl[i1 - off];
        __syncthreads();
        if (i0 < nd) lexcl[i0] += a0;
        if (i1 < nd) lexcl[i1] += a1;
        __syncthreads();
    }
    for (int i = t; i < nd; i += 256) {
        lexcl[i] -= lhist[i];                        // exclusive
        rowptr[d0 + i] = base + lexcl[i];
    }
    __syncthreads();
    for (int i = t; i < n; i += 256) {
        unsigned r = recs[i];
        int li = (int)(r & 0xFFFFu) - d0;
        int pos = base + lexcl[li] + atomicAdd(&lcur[li], 1);
        colidx[pos] = (int)(r >> 16);
    }
}

// ---------------- generic GEMM (K=39 encoder-1 only) ----------------
template <int NC, bool RELU>
__global__ __launch_bounds__(256) void gemm_small_kernel(const float* __restrict__ A,
                                                         const float* __restrict__ B,
                                                         const float* __restrict__ bias,
                                                         float* __restrict__ C, int M, int K) {
    constexpr int TM = 32;
    constexpr int GROUPS = 256 / NC;
    constexpr int RPG = TM / GROUPS;
    constexpr int KC = 64;
    __shared__ float As[TM * 128];
    __shared__ float Bs[KC * NC];
    int t = threadIdx.x;
    int i0 = blockIdx.x * TM;

    int rows = M - i0; if (rows > TM) rows = TM;
    for (int idx = t; idx < rows * K; idx += 256) {
        int r = idx / K, k = idx - r * K;
        As[r * K + k] = A[(size_t)(i0 + r) * K + k];
    }

    int col = t % NC, grp = t / NC;
    int rg0 = grp * RPG;
    float acc[RPG];
#pragma unroll
    for (int r = 0; r < RPG; ++r) acc[r] = 0.f;

    for (int k0 = 0; k0 < K; k0 += KC) {
        int kc = K - k0; if (kc > KC) kc = KC;
        __syncthreads();
        for (int idx = t; idx < kc * NC; idx += 256) Bs[idx] = B[(size_t)k0 * NC + idx];
        __syncthreads();
        for (int k = 0; k < kc; ++k) {
            float bv = Bs[k * NC + col];
#pragma unroll
            for (int r = 0; r < RPG; ++r) acc[r] += As[(rg0 + r) * K + k0 + k] * bv;
        }
    }

    float bb = bias ? bias[col] : 0.f;
#pragma unroll
    for (int r = 0; r < RPG; ++r) {
        int i = i0 + rg0 + r;
        if (i < M) {
            float v = acc[r] + bb;
            if (RELU) v = v > 0.f ? v : 0.f;
            C[(size_t)i * NC + col] = v;
        }
    }
}

// ---------------- fast GEMM 128x128, 24KB LDS; EPI: packed-bf16 xp + es/ed ----------------
template <bool BIAS, bool EPI>
__global__ __launch_bounds__(256) void gemm128_kernel(const float* __restrict__ A,
                                                      const float* __restrict__ B,
                                                      const float* __restrict__ bias,
                                                      float* __restrict__ C,
                                                      unsigned* __restrict__ XP,
                                                      const float* __restrict__ a_s,
                                                      const float* __restrict__ a_d,
                                                      float* __restrict__ es,
                                                      float* __restrict__ ed, int M) {
    __shared__ float As[64 * 32];    // 8 KB : 64 rows x 32-k chunk
    __shared__ float Bs[32 * 128];   // 16 KB: 32-k chunk x 128 cols
    int t = threadIdx.x;
    int i0 = blockIdx.x * 64;
    int tc = t & 31;                 // cols tc*4 .. tc*4+3
    int tr = t >> 5;
    int r0 = tr * 8;
    int c0 = tc * 4;

    float acc[8][4];
#pragma unroll
    for (int i = 0; i < 8; ++i)
#pragma unroll
        for (int j = 0; j < 4; ++j) acc[i][j] = 0.f;

    for (int k0 = 0; k0 < 128; k0 += 32) {
        __syncthreads();
#pragma unroll
        for (int q = 0; q < 2; ++q) {
            int idx = t + q * 256;           // 0..511
            int r = idx >> 3, kq = idx & 7;
            float4 v4 = make_float4(0.f, 0.f, 0.f, 0.f);
            if (i0 + r < M) v4 = *(const float4*)&A[(size_t)(i0 + r) * 128 + k0 + kq * 4];
            *(float4*)&As[r * 32 + kq * 4] = v4;
        }
#pragma unroll
        for (int q = 0; q < 4; ++q) {
            int idx = (t + q * 256) * 4;
            *(float4*)&Bs[idx] = *(const float4*)&B[(size_t)k0 * 128 + idx];
        }
        __syncthreads();
#pragma unroll 8
        for (int k = 0; k < 32; k += 4) {
            float4 a4[8];
#pragma unroll
            for (int i = 0; i < 8; ++i)
                a4[i] = *(const float4*)&As[(r0 + i) * 32 + k];
            float4 b4[4];
#pragma unroll
            for (int kk = 0; kk < 4; ++kk)
                b4[kk] = *(const float4*)&Bs[(k + kk) * 128 + c0];
#pragma unroll
            for (int i = 0; i < 8; ++i) {
                const float* av = (const float*)&a4[i];
#pragma unroll
                for (int kk = 0; kk < 4; ++kk) {
                    acc[i][0] += av[kk] * b4[kk].x;
                    acc[i][1] += av[kk] * b4[kk].y;
                    acc[i][2] += av[kk] * b4[kk].z;
                    acc[i][3] += av[kk] * b4[kk].w;
                }
            }
        }
    }

    if (!EPI) {
        float4 bias4 = make_float4(0.f, 0.f, 0.f, 0.f);
        if (BIAS) bias4 = *(const float4*)&bias[c0];
#pragma unroll
        for (int i = 0; i < 8; ++i) {
            int row = i0 + r0 + i;
            if (row < M) {
                float4 o;
                o.x = acc[i][0] + bias4.x;
                o.y = acc[i][1] + bias4.y;
                o.z = acc[i][2] + bias4.z;
                o.w = acc[i][3] + bias4.w;
                *(float4*)&C[(size_t)row * 128 + c0] = o;
            }
        }
    } else {
        // xp as packed bf16: word w holds channels (2w, 2w+1); this thread owns words c0/2, c0/2+1
#pragma unroll
        for (int i = 0; i < 8; ++i) {
            int row = i0 + r0 + i;
            if (row < M) {
                uint2 o;
                o.x = pack_bf16(acc[i][0], acc[i][1]);
                o.y = pack_bf16(acc[i][2], acc[i][3]);
                *(uint2*)&XP[(size_t)row * 64 + tc * 2] = o;
            }
        }
        // es/ed from exact fp32 acc; head hd = tc>>3; reduce over 8-lane octet
        int hd = tc >> 3;
        float4 s4 = *(const float4*)&a_s[c0];
        float4 d4 = *(const float4*)&a_d[c0];
#pragma unroll
        for (int i = 0; i < 8; ++i) {
            int row = i0 + r0 + i;
            float s = acc[i][0] * s4.x + acc[i][1] * s4.y + acc[i][2] * s4.z + acc[i][3] * s4.w;
            float d = acc[i][0] * d4.x + acc[i][1] * d4.y + acc[i][2] * d4.z + acc[i][3] * d4.w;
#pragma unroll
            for (int off = 4; off >= 1; off >>= 1) {
                s += __shfl_xor(s, off);
                d += __shfl_xor(d, off);
            }
            if ((tc & 7) == 0 && row < M) {
                es[row * 4 + hd] = s;
                ed[row * 4 + hd] = d;
            }
        }
    }
}

// ---------------- head GEMMs fully fused: h -> out (impact+timing), 24KB LDS ----------------
__global__ __launch_bounds__(256) void gemm_heads_kernel(const float* __restrict__ A,
                                                         const float* __restrict__ iw1,
                                                         const float* __restrict__ ib1,
                                                         const float* __restrict__ tw1,
                                                         const float* __restrict__ tb1,
                                                         const float* __restrict__ iw2,
                                                         const float* __restrict__ ib2,
                                                         const float* __restrict__ tw2,
                                                         const float* __restrict__ tb2,
                                                         float* __restrict__ out, int M) {
    __shared__ float As[64 * 32];
    __shared__ float Bs[32 * 128];
    int t = threadIdx.x;
    int i0 = blockIdx.x * 64;
    int tc = t & 31;
    int tr = t >> 5;
    int r0 = tr * 8;
    int c0 = tc * 4;                 // virtual col (0-63 impact, 64-127 timing)

    float acc[8][4];
#pragma unroll
    for (int i = 0; i < 8; ++i)
#pragma unroll
        for (int j = 0; j < 4; ++j) acc[i][j] = 0.f;

    for (int k0 = 0; k0 < 128; k0 += 32) {
        __syncthreads();
#pragma unroll
        for (int q = 0; q < 2; ++q) {
            int idx = t + q * 256;
            int r = idx >> 3, kq = idx & 7;
            float4 v4 = make_float4(0.f, 0.f, 0.f, 0.f);
            if (i0 + r < M) v4 = *(const float4*)&A[(size_t)(i0 + r) * 128 + k0 + kq * 4];
            *(float4*)&As[r * 32 + kq * 4] = v4;
        }
#pragma unroll
        for (int q = 0; q < 4; ++q) {
            int idx = (t + q * 256) * 4;       // flat into [32][128]
            int k = idx >> 7, cl = idx & 127;
            float4 v4 = (cl < 64)
                ? *(const float4*)&iw1[(size_t)(k0 + k) * 64 + cl]
                : *(const float4*)&tw1[(size_t)(k0 + k) * 64 + (cl - 64)];
            *(float4*)&Bs[idx] = v4;
        }
        __syncthreads();
#pragma unroll 8
        for (int k = 0; k < 32; k += 4) {
            float4 a4[8];
#pragma unroll
            for (int i = 0; i < 8; ++i)
                a4[i] = *(const float4*)&As[(r0 + i) * 32 + k];
            float4 b4[4];
#pragma unroll
            for (int kk = 0; kk < 4; ++kk)
                b4[kk] = *(const float4*)&Bs[(k + kk) * 128 + c0];
#pragma unroll
            for (int i = 0; i < 8; ++i) {
                const float* av = (const float*)&a4[i];
#pragma unroll
                for (int kk = 0; kk < 4; ++kk) {
                    acc[i][0] += av[kk] * b4[kk].x;
                    acc[i][1] += av[kk] * b4[kk].y;
                    acc[i][2] += av[kk] * b4[kk].z;
                    acc[i][3] += av[kk] * b4[kk].w;
                }
            }
        }
    }

    bool isimp = (tc < 16);
    int lc = isimp ? c0 : (c0 - 64);
    float v[8][4];
#pragma unroll
    for (int i = 0; i < 8; ++i)
#pragma unroll
        for (int j = 0; j < 4; ++j) {
            float b = isimp ? ib1[lc + j] : tb1[lc + j];
            float x = acc[i][j] + b;
            v[i][j] = x > 0.f ? x : 0.f;
        }
#pragma unroll
    for (int i = 0; i < 8; ++i) {
        int row = i0 + r0 + i;
        if (isimp) {
#pragma unroll
            for (int c = 0; c < 3; ++c) {
                float pc = v[i][0] * iw2[(lc + 0) * 3 + c] + v[i][1] * iw2[(lc + 1) * 3 + c]
                         + v[i][2] * iw2[(lc + 2) * 3 + c] + v[i][3] * iw2[(lc + 3) * 3 + c];
#pragma unroll
                for (int off = 8; off >= 1; off >>= 1) pc += __shfl_xor(pc, off);
                if (tc == 0 && row < M) out[(size_t)row * 3 + c] = pc + ib2[c];
            }
        } else {
#pragma unroll
            for (int d = 0; d < 2; ++d) {
                float pd = v[i][0] * tw2[(lc + 0) * 2 + d] + v[i][1] * tw2[(lc + 1) * 2 + d]
                         + v[i][2] * tw2[(lc + 2) * 2 + d] + v[i][3] * tw2[(lc + 3) * 2 + d];
#pragma unroll
                for (int off = 8; off >= 1; off >>= 1) pd += __shfl_xor(pd, off);
                if (tc == 16 && row < M) {
                    float a = pd + tb2[d];
                    float sp = a > 20.f ? a : log1pf(__expf(a));
                    out[(size_t)(NN * 3) + (size_t)row * 2 + d] = sp;
                }
            }
        }
    }
}

// ---------------- gat: packed-bf16 xp gather; wave per node; lane owns channels (2l,2l+1) ----------------
__global__ __launch_bounds__(256) void gat_kernel(const unsigned* __restrict__ xpk,
                                                  const float* __restrict__ es,
                                                  const float* __restrict__ ed,
                                                  const int* __restrict__ rowptr,
                                                  const int* __restrict__ colidx,
                                                  float* __restrict__ h,   // in-out (residual)
                                                  const float* __restrict__ bc,
                                                  const float* __restrict__ g,
                                                  const float* __restrict__ be) {
    int wv = threadIdx.x >> 6, l = threadIdx.x & 63;
    int v = blockIdx.x * 4 + wv;
    if (v >= NN) return;
    int s0 = rowptr[v], s1 = rowptr[v + 1];
    int hd = l >> 4;                       // head of channels 2l, 2l+1
    float edv = ed[v * 4 + hd];
    float ax = 0.f, ay = 0.f, den = 0.f;   // den identical across the 16 lanes of a head
    int p = s0;
    for (; p + 8 <= s1; p += 8) {          // 8 gathers in flight
        int u[8];
#pragma unroll
        for (int q = 0; q < 8; ++q) u[q] = colidx[p + q];
        unsigned xw[8];
#pragma unroll
        for (int q = 0; q < 8; ++q) xw[q] = xpk[(size_t)u[q] * 64 + l];
        float w[8];
#pragma unroll
        for (int q = 0; q < 8; ++q) {
            float e = es[u[q] * 4 + hd] + edv;
            e = e > 0.f ? e : 0.2f * e;
            w[q] = __expf(e);              // no max-shift: |e| small, softmax shift-invariant
        }
#pragma unroll
        for (int q = 0; q < 8; ++q) {
            float2 x = unpack_bf16(xw[q]);
            ax += w[q] * x.x; ay += w[q] * x.y; den += w[q];
        }
    }
    for (; p < s1; ++p) {
        int u = colidx[p];
        float e = es[u * 4 + hd] + edv; e = e > 0.f ? e : 0.2f * e;
        float w = __expf(e);
        float2 x = unpack_bf16(xpk[(size_t)u * 64 + l]);
        ax += w * x.x; ay += w * x.y;
        den += w;
    }
    float rd = 1.f / den;

    float2 h2  = *(const float2*)&h[(size_t)v * 128 + 2 * l];
    float2 bc2 = *(const float2*)&bc[2 * l];
    float y0 = ax * rd + bc2.x + h2.x;
    float y1 = ay * rd + bc2.y + h2.y;

    float s = y0 + y1;
#pragma unroll
    for (int off = 32; off >= 1; off >>= 1) s += __shfl_xor(s, off);
    float mean = s * (1.f / 128.f);
    float d0 = y0 - mean, d1 = y1 - mean;
    float vv = d0 * d0 + d1 * d1;
#pragma unroll
    for (int off = 32; off >= 1; off >>= 1) vv += __shfl_xor(vv, off);
    float rstd = rsqrtf(vv * (1.f / 128.f) + 1e-5f);
    float2 g2  = *(const float2*)&g[2 * l];
    float2 be2 = *(const float2*)&be[2 * l];
    float z0 = d0 * rstd * g2.x + be2.x;
    float z1 = d1 * rstd * g2.y + be2.y;
    float2 o;
    o.x = z0 > 0.f ? z0 : 0.f;
    o.y = z1 > 0.f ? z1 : 0.f;
    *(float2*)&h[(size_t)v * 128 + 2 * l] = o;
}

extern "C" void kernel_launch(void* const* d_in, const int* in_sizes, int n_in,
                              void* d_out, int out_size, void* d_ws, size_t ws_size,
                              hipStream_t stream) {
    const float* x      = (const float*)d_in[0];
    const int*   ei     = (const int*)d_in[1];
    const float* enc_w1 = (const float*)d_in[2];
    const float* enc_b1 = (const float*)d_in[3];
    const float* enc_w2 = (const float*)d_in[4];
    const float* enc_b2 = (const float*)d_in[5];
    const float *W[3], *as_[3], *ad_[3], *bc[3], *g[3], *be[3];
    for (int l = 0; l < 3; ++l) {
        W[l]   = (const float*)d_in[6 + l * 6 + 0];
        as_[l] = (const float*)d_in[6 + l * 6 + 1];
        ad_[l] = (const float*)d_in[6 + l * 6 + 2];
        bc[l]  = (const float*)d_in[6 + l * 6 + 3];
        g[l]   = (const float*)d_in[6 + l * 6 + 4];
        be[l]  = (const float*)d_in[6 + l * 6 + 5];
    }
    const float* imp_w1 = (const float*)d_in[24];
    const float* imp_b1 = (const float*)d_in[25];
    const float* imp_w2 = (const float*)d_in[26];
    const float* imp_b2 = (const float*)d_in[27];
    const float* tim_w1 = (const float*)d_in[28];
    const float* tim_b1 = (const float*)d_in[29];
    const float* tim_w2 = (const float*)d_in[30];
    const float* tim_b2 = (const float*)d_in[31];

    int* gcursor = (int*)d_ws;               // NPART
    int* pbase   = gcursor + NPART;          // NPART + pad
    int* rowptr  = pbase + NPART + 64;       // NN+1
    int* colidx  = rowptr + NN + 1;          // ETOT
    uintptr_t pb = (uintptr_t)(colidx + ETOT);
    pb = (pb + 255) & ~(uintptr_t)255;
    unsigned* pbuf = (unsigned*)pb;          // NPART*PCAP (7.2 MB)
    uintptr_t fb = (uintptr_t)(pbuf + (size_t)NPART * PCAP);
    fb = (fb + 255) & ~(uintptr_t)255;
    float* es = (float*)fb;                  // NN*4
    float* ed = es + (size_t)NN * 4;         // NN*4
    float* h  = ed + (size_t)NN * 4;         // NN*128 fp32
    float* xpf = h + (size_t)NN * 128;       // region sized NN*128 floats
    unsigned* xpk = (unsigned*)xpf;          // packed bf16 uses first half
    float* tmp = xpf;                        // enc1 scratch aliases (dead before xpk lives)

    hipMemsetAsync(gcursor, 0, NPART * sizeof(int), stream);
    pass1_kernel<<<512, 256, 0, stream>>>(ei, gcursor, pbuf);
    scan_part_kernel<<<1, NPART, 0, stream>>>(gcursor, pbase, rowptr + NN);
    pass2_kernel<<<NPART, 256, 0, stream>>>(pbuf, gcursor, pbase, rowptr, colidx);

    const int GB64 = (NN + 63) / 64;
    gemm_small_kernel<128, true><<<(NN + 31) / 32, 256, 0, stream>>>(x, enc_w1, enc_b1, tmp, NN, FINDIM);
    gemm128_kernel<true, false><<<GB64, 256, 0, stream>>>(tmp, enc_w2, enc_b2, h, nullptr,
                                                          nullptr, nullptr, nullptr, nullptr, NN);

    for (int l = 0; l < 3; ++l) {
        gemm128_kernel<false, true><<<GB64, 256, 0, stream>>>(h, W[l], nullptr, nullptr, xpk,
                                                              as_[l], ad_[l], es, ed, NN);
        gat_kernel<<<(NN + 3) / 4, 256, 0, stream>>>(xpk, es, ed, rowptr, colidx, h,
                                                     bc[l], g[l], be[l]);
    }

    gemm_heads_kernel<<<GB64, 256, 0, stream>>>(h, imp_w1, imp_b1, tim_w1, tim_b1,
                                                imp_w2, imp_b2, tim_w2, tim_b2,
                                                (float*)d_out, NN);
}